// Round 2
// baseline (408.893 us; speedup 1.0000x reference)
//
#include <hip/hip_runtime.h>
#include <hip/hip_bf16.h>
#include <hip/hip_fp16.h>
#include <math.h>

// Problem constants
#define BB 2
#define TT 2048
#define DD 1024
#define HH 16
#define DK 64
#define KT 128            // keys per attention tile

typedef _Float16 f16x8 __attribute__((ext_vector_type(8)));
typedef __fp16 fp16x2 __attribute__((ext_vector_type(2)));
typedef __attribute__((ext_vector_type(4))) float f32x4;
typedef __attribute__((ext_vector_type(2))) float f32x2;

// async 16B global->LDS (lane i writes ldsbase + i*16)
static __device__ __forceinline__ void g2lds16(const void* g, void* l) {
    __builtin_amdgcn_global_load_lds(
        (const __attribute__((address_space(1))) unsigned int*)g,
        (__attribute__((address_space(3))) unsigned int*)l, 16, 0, 0);
}

// w = (1 - acos(clip(s,±0.999))/pi)^8 for a pair; rs accumulates pair sums.
// acos/pi via A&S 4.4.45 deg-3 (|err|<=5e-5 rad); reference's max(.,1e-6)
// is dead (clamp => t >= 0.0142). float2 ops lower to v_pk_* on gfx950.
// Magnitude-only clamp (abs folds into v_min modifier), packed 1-ax, and
// branch-free t = 0.5 + copysign(0.5 - uq, s).
static __device__ __forceinline__ f32x2 w8pair(f32x2 s, f32x2& rs) {
    f32x2 ax;
    ax.x = fminf(fabsf(s.x), 0.999f);
    ax.y = fminf(fabsf(s.y), 0.999f);
    f32x2 p = ax * -0.0059617f + 0.0236380f;
    p = p * ax + (-0.0675180f);
    p = p * ax + 0.49997851f;
    f32x2 om = 1.0f - ax;
    f32x2 u;
    u.x = sqrtf(om.x);
    u.y = sqrtf(om.y);
    f32x2 uq = u * p;
    f32x2 e = 0.5f - uq;
    f32x2 t;
    t.x = 0.5f + copysignf(e.x, s.x);
    t.y = 0.5f + copysignf(e.y, s.y);
    f32x2 t2 = t * t;
    f32x2 t4 = t2 * t2;
    f32x2 t8 = t4 * t4;
    rs += t8;
    return t8;
}
// one-instruction f16 pair pack (RTZ; |err|<=2^-11 rel, fine for W)
static __device__ __forceinline__ int packh2(f32x2 v) {
    union { fp16x2 h; int i; } u;
    u.h = __builtin_amdgcn_cvt_pkrtz(v.x, v.y);
    return u.i;
}

// ---------------------------------------------------------------------------
// fp32 -> f16 convert (n multiple of 2048; 8 elems/thread)
// ---------------------------------------------------------------------------
__global__ __launch_bounds__(256) void cvt_kernel(
    const float* __restrict__ src, _Float16* __restrict__ dst)
{
    const int i = (blockIdx.x * 256 + threadIdx.x) * 8;
    float4 a = *(const float4*)(src + i);
    float4 b = *(const float4*)(src + i + 4);
    union { _Float16 h[8]; int4 v; } u;
    u.h[0] = (_Float16)a.x; u.h[1] = (_Float16)a.y;
    u.h[2] = (_Float16)a.z; u.h[3] = (_Float16)a.w;
    u.h[4] = (_Float16)b.x; u.h[5] = (_Float16)b.y;
    u.h[6] = (_Float16)b.z; u.h[7] = (_Float16)b.w;
    *(int4*)(dst + i) = u.v;
}

// 4 weights at once (blockIdx.y selects)
__global__ __launch_bounds__(256) void wcvt_kernel(
    const float* __restrict__ s0, const float* __restrict__ s1,
    const float* __restrict__ s2, const float* __restrict__ s3,
    _Float16* __restrict__ d0, _Float16* __restrict__ d1,
    _Float16* __restrict__ d2, _Float16* __restrict__ d3)
{
    const float* s; _Float16* d;
    switch (blockIdx.y) {
        case 0: s = s0; d = d0; break;
        case 1: s = s1; d = d1; break;
        case 2: s = s2; d = d2; break;
        default: s = s3; d = d3; break;
    }
    const int i = (blockIdx.x * 256 + threadIdx.x) * 8;
    float4 a = *(const float4*)(s + i);
    float4 b = *(const float4*)(s + i + 4);
    union { _Float16 h[8]; int4 v; } u;
    u.h[0] = (_Float16)a.x; u.h[1] = (_Float16)a.y;
    u.h[2] = (_Float16)a.z; u.h[3] = (_Float16)a.w;
    u.h[4] = (_Float16)b.x; u.h[5] = (_Float16)b.y;
    u.h[6] = (_Float16)b.z; u.h[7] = (_Float16)b.w;
    *(int4*)(d + i) = u.v;
}

// ---------------------------------------------------------------------------
// Pure-f16 async MFMA GEMM: C[M,N] = (Ah [+ Al]) [M,K] @ B[N,K]^T (+bias).
// Inputs pre-converted f16. 64x128 tile, BK=64, 4 waves (2x2).
// LDS chunk-major [kc][row][8] so global_load_lds lane->slot is contiguous
// and frag ds_read_b128 is ~2-way bank aliased (free).
// NPROD=1: projections (single product). NPROD=2: + Al·B (Wo GEMM).
// ---------------------------------------------------------------------------
template<int NPROD>
__global__ __launch_bounds__(256) void gemm_f16(
    const _Float16* __restrict__ Ah_g, const _Float16* __restrict__ Al_g,
    const _Float16* __restrict__ B_g, const float* __restrict__ bias,
    float* __restrict__ C, int M, int N, int K, int hasBias)
{
    __shared__ _Float16 Ahs[8][64][8];    //  8 KB
    __shared__ _Float16 Als[8][64][8];    //  8 KB (unused traffic if NPROD=1)
    __shared__ _Float16 Bhs[8][128][8];   // 16 KB

    const int t    = threadIdx.x;
    const int m0   = blockIdx.y * 64;
    const int n0   = blockIdx.x * 128;
    const int lane = t & 63;
    const int w    = t >> 6;
    const int wm   = w >> 1;
    const int wn   = w & 1;
    const int l15  = lane & 15;
    const int quad = lane >> 4;

    f32x4 acc[2][4];
#pragma unroll
    for (int i = 0; i < 2; ++i)
#pragma unroll
        for (int j = 0; j < 4; ++j) acc[i][j] = (f32x4)0.f;

    for (int k0 = 0; k0 < K; k0 += 64) {
        __syncthreads();   // previous chunk's frag reads done
        // staging: wave w handles kc = 2w, 2w+1
#pragma unroll
        for (int i = 0; i < 2; ++i) {
            const int cc = w * 2 + i;
            g2lds16(Ah_g + (size_t)(m0 + lane) * K + k0 + cc * 8, &Ahs[cc][0][0]);
            if (NPROD == 2)
                g2lds16(Al_g + (size_t)(m0 + lane) * K + k0 + cc * 8, &Als[cc][0][0]);
#pragma unroll
            for (int half = 0; half < 2; ++half)
                g2lds16(B_g + (size_t)(n0 + half * 64 + lane) * K + k0 + cc * 8,
                        &Bhs[cc][half * 64][0]);
        }
        __syncthreads();   // vmcnt drained

#pragma unroll
        for (int kh = 0; kh < 2; ++kh) {
            f16x8 ah[2], bh[4];
#pragma unroll
            for (int tm = 0; tm < 2; ++tm)
                ah[tm] = *(const f16x8*)&Ahs[kh * 4 + quad][wm * 32 + tm * 16 + l15][0];
#pragma unroll
            for (int tn = 0; tn < 4; ++tn)
                bh[tn] = *(const f16x8*)&Bhs[kh * 4 + quad][wn * 64 + tn * 16 + l15][0];
#pragma unroll
            for (int tm = 0; tm < 2; ++tm)
#pragma unroll
                for (int tn = 0; tn < 4; ++tn)
                    acc[tm][tn] = __builtin_amdgcn_mfma_f32_16x16x32_f16(
                        ah[tm], bh[tn], acc[tm][tn], 0, 0, 0);
            if (NPROD == 2) {
                f16x8 al[2];
#pragma unroll
                for (int tm = 0; tm < 2; ++tm)
                    al[tm] = *(const f16x8*)&Als[kh * 4 + quad][wm * 32 + tm * 16 + l15][0];
#pragma unroll
                for (int tm = 0; tm < 2; ++tm)
#pragma unroll
                    for (int tn = 0; tn < 4; ++tn)
                        acc[tm][tn] = __builtin_amdgcn_mfma_f32_16x16x32_f16(
                            al[tm], bh[tn], acc[tm][tn], 0, 0, 0);
            }
        }
    }

#pragma unroll
    for (int tm = 0; tm < 2; ++tm)
#pragma unroll
        for (int tn = 0; tn < 4; ++tn) {
            const int col  = n0 + wn * 64 + tn * 16 + l15;
            const float bv = hasBias ? bias[col] : 0.f;
            const int rowb = m0 + wm * 32 + tm * 16 + quad * 4;
#pragma unroll
            for (int r = 0; r < 4; ++r)
                C[(size_t)(rowb + r) * N + col] = acc[tm][tn][r] + bv;
        }
}

// ---------------------------------------------------------------------------
// Normalize each 64-wide head segment; emit f16 at [b][h][t][dk].
// ---------------------------------------------------------------------------
__global__ __launch_bounds__(256) void norm_kernel(
    const float* __restrict__ X, _Float16* __restrict__ H)
{
    const int seg  = blockIdx.x * 4 + (threadIdx.x >> 6);
    const int lane = threadIdx.x & 63;
    const int row  = seg >> 4;   // b*T + t
    const int h    = seg & 15;
    float v = X[(size_t)row * DD + h * DK + lane];
    float s = v * v;
    s += __shfl_xor(s, 1);
    s += __shfl_xor(s, 2);
    s += __shfl_xor(s, 4);
    s += __shfl_xor(s, 8);
    s += __shfl_xor(s, 16);
    s += __shfl_xor(s, 32);
    float n = sqrtf(s);
    float vn = v / fmaxf(n, 1e-12f);
    const int b  = row >> 11;
    const int tt = row & 2047;
    H[((size_t)(b * HH + h) * TT + tt) * DK + lane] = (_Float16)vn;
}

// ---------------------------------------------------------------------------
// V -> f16 transposed [b][h][d][T].
// ---------------------------------------------------------------------------
__global__ __launch_bounds__(256) void vtrans_kernel(
    const float* __restrict__ V0, _Float16* __restrict__ Vt)
{
    __shared__ _Float16 Vtmp[64][72];
    const int t  = threadIdx.x;
    const int t0 = blockIdx.x * 64;
    const int h  = blockIdx.y;
    const int b  = blockIdx.z;

    {
        const int i  = t >> 2;            // token row 0..63
        const int jc = (t & 3) * 16;      // dim chunk
        const float* src = V0 + (size_t)(b * TT + t0 + i) * DD + h * DK + jc;
#pragma unroll
        for (int c = 0; c < 4; ++c) {
            float4 v = *(const float4*)(src + c * 4);
            Vtmp[jc + c * 4 + 0][i] = (_Float16)v.x;
            Vtmp[jc + c * 4 + 1][i] = (_Float16)v.y;
            Vtmp[jc + c * 4 + 2][i] = (_Float16)v.z;
            Vtmp[jc + c * 4 + 3][i] = (_Float16)v.w;
        }
    }
    __syncthreads();
    {
        const int d  = t >> 2;
        const int kc = (t & 3) * 16;
        _Float16* dst = Vt + ((size_t)((b * HH + h) * DK + d)) * TT + t0 + kc;
        *(int4*)(dst)     = *(const int4*)&Vtmp[d][kc];
        *(int4*)(dst + 8) = *(const int4*)&Vtmp[d][kc + 8];
    }
}

// ---------------------------------------------------------------------------
// MFMA angular attention v7 — all-f16. Grid (T/64, H, B), 256 threads.
// v7: K and V MFMA fragments are 16B-contiguous in Kh/Vt global layouts and
// the per-(b,h) K/V (512 KB) is L2-resident across the 32 q-blocks — so the
// LDS staging round-trip for K/V (32 KB/tile g2lds + 96 KB/tile ds_reads,
// 4x-redundant bv) is pure LDS-port overhead. Drop it: load kf/bv fragments
// straight from global. Only Ws stays in LDS (the W transpose), ping-ponged
// so ONE barrier per tile covers both hazards (write->read of tile t, and
// read->write of tile t+2 via tile t+1's barrier). No vmcnt(0) drains.
// kf for tile t+1 prefetched right after the barrier (hidden under phase B).
// LDS 36 KB, launch_bounds(256,4) -> 4 blocks/CU (16 waves, was 12).
// ---------------------------------------------------------------------------
__global__ __launch_bounds__(256, 4) void attn_kernel(
    const _Float16* __restrict__ Qh_g, const _Float16* __restrict__ Kh_g,
    const _Float16* __restrict__ Vt_g,
    _Float16* __restrict__ Oh, _Float16* __restrict__ Ol)
{
    __shared__ _Float16 Ws[2][64][136];  // [pp][q][key]  34816 B
    __shared__ float Rbuf[4][64];        //                1024 B
    __shared__ float Rfin[64];           //                 256 B

    const int t    = threadIdx.x;
    const int lane = t & 63;
    const int w    = t >> 6;
    const int l15  = lane & 15;
    const int quad = lane >> 4;
    const int q0   = blockIdx.x * 64;
    const int h    = blockIdx.y;
    const int b    = blockIdx.z;
    const size_t bh = (size_t)(b * HH + h);

    // Q fragments in registers (loaded once, L2-served)
    f16x8 qf[4][2];
#pragma unroll
    for (int qt = 0; qt < 4; ++qt)
#pragma unroll
        for (int s = 0; s < 2; ++s)
            qf[qt][s] = *(const f16x8*)(Qh_g + (bh * TT + q0 + qt * 16 + l15) * DK
                                        + s * 32 + quad * 8);

    f32x4 acc[4];    // O[16q x 64d] for q-tile w
#pragma unroll
    for (int j = 0; j < 4; ++j) acc[j] = (f32x4)0.f;
    f32x2 rs2[4];
#pragma unroll
    for (int j = 0; j < 4; ++j) rs2[j] = (f32x2)0.f;

    const _Float16* kh_g = Kh_g + bh * TT * DK;
    const _Float16* vt_g = Vt_g + bh * (size_t)DK * TT;

    // K fragments for tile 0 (wave's 32 keys; 16B contiguous per lane)
    f16x8 kf[2][2];    // [s][mt]
#pragma unroll
    for (int s = 0; s < 2; ++s)
#pragma unroll
        for (int mt = 0; mt < 2; ++mt)
            kf[s][mt] = *(const f16x8*)(kh_g
                + (size_t)(w * 32 + mt * 16 + l15) * DK + s * 32 + quad * 8);

    int p = 0;
    for (int k0 = 0; k0 < TT; k0 += KT, p ^= 1) {
        // Phase A: S^T for wave's 32 keys x 64 q, transform, write Ws[p]
#pragma unroll
        for (int qt = 0; qt < 4; ++qt) {
            f32x4 c_[2];
            c_[0] = (f32x4)0.f;
            c_[1] = (f32x4)0.f;
#pragma unroll
            for (int s = 0; s < 2; ++s) {
#pragma unroll
                for (int mt = 0; mt < 2; ++mt)
                    c_[mt] = __builtin_amdgcn_mfma_f32_16x16x32_f16(
                        kf[s][mt], qf[qt][s], c_[mt], 0, 0, 0);
            }
#pragma unroll
            for (int mt = 0; mt < 2; ++mt) {
                f32x2 p01, p23;
                p01.x = c_[mt][0]; p01.y = c_[mt][1];
                p23.x = c_[mt][2]; p23.y = c_[mt][3];
                f32x2 w01 = w8pair(p01, rs2[qt]);
                f32x2 w23 = w8pair(p23, rs2[qt]);
                int2 pk;
                pk.x = packh2(w01);
                pk.y = packh2(w23);
                *(int2*)&Ws[p][qt * 16 + l15][w * 32 + mt * 16 + quad * 4] = pk;
            }
        }
        __syncthreads();   // Ws[p] ready (also fences Ws[p^1] reads of t-1)

        // prefetch K fragments for next tile (consumed ~5K cycles later)
        if (k0 + KT < TT) {
#pragma unroll
            for (int s = 0; s < 2; ++s)
#pragma unroll
                for (int mt = 0; mt < 2; ++mt)
                    kf[s][mt] = *(const f16x8*)(kh_g
                        + (size_t)(k0 + KT + w * 32 + mt * 16 + l15) * DK
                        + s * 32 + quad * 8);
        }

        // Phase B: PV for q-tile w over all 128 keys; bv straight from L2
#pragma unroll
        for (int kstep = 0; kstep < 4; ++kstep) {
            f16x8 av = *(const f16x8*)&Ws[p][16 * w + l15][kstep * 32 + quad * 8];
#pragma unroll
            for (int nd = 0; nd < 4; ++nd) {
                f16x8 bv = *(const f16x8*)(vt_g
                    + (size_t)(nd * 16 + l15) * TT + k0 + kstep * 32 + quad * 8);
                acc[nd] = __builtin_amdgcn_mfma_f32_16x16x32_f16(
                    av, bv, acc[nd], 0, 0, 0);
            }
        }
    }

    // rowsum: rs2[qt] covers q = qt*16+l15 over wave's keys
#pragma unroll
    for (int qt = 0; qt < 4; ++qt) {
        float pr = rs2[qt].x + rs2[qt].y;
        pr += __shfl_xor(pr, 16);
        pr += __shfl_xor(pr, 32);
        if (quad == 0) Rbuf[w][qt * 16 + l15] = pr;
    }
    __syncthreads();
    if (t < 64) {
        float s = Rbuf[0][t] + Rbuf[1][t] + Rbuf[2][t] + Rbuf[3][t];
        Rfin[t] = 1.f / (s + 1e-6f);
    }
    __syncthreads();

    // store: O split hi/lo f16 (feeds the 2-product Wo GEMM)
#pragma unroll
    for (int r = 0; r < 4; ++r) {
        const int q = 16 * w + quad * 4 + r;
        const float inv = Rfin[q];
        const size_t base = (size_t)(b * TT + q0 + q) * DD + h * DK + l15;
#pragma unroll
        for (int nd = 0; nd < 4; ++nd) {
            float v = acc[nd][r] * inv;
            _Float16 hv = (_Float16)v;
            Oh[base + nd * 16] = hv;
            Ol[base + nd * 16] = (_Float16)(v - (float)hv);
        }
    }
}

// ---------------------------------------------------------------------------
extern "C" void kernel_launch(void* const* d_in, const int* in_sizes, int n_in,
                              void* d_out, int out_size, void* d_ws, size_t ws_size,
                              hipStream_t stream)
{
    const float* x  = (const float*)d_in[0];
    const float* Wq = (const float*)d_in[1];
    const float* Wk = (const float*)d_in[2];
    const float* Wv = (const float*)d_in[3];
    const float* Wo = (const float*)d_in[4];
    const float* bo = (const float*)d_in[5];
    float* out = (float*)d_out;

    const int M = BB * TT;   // 4096
    const int N = DD;
    const int K = DD;

    const size_t MB = 1024 * 1024;
    char* ws = (char*)d_ws;
    // [0,8):   xh f16                -> Kh f16 (after projections)
    // [8,16):  Wqh,Wkh,Wvh,Woh f16 (2 MB each; Woh persists)
    // [16,32): Q0 fp32               -> Oh [16,24) + Ol [24,32) (after norm Q)
    // [32,48): K0 fp32               -> Qh [32,40) + Vt [40,48) (after norm K)
    // [48,64): V0 fp32
    _Float16* xh  = (_Float16*)(ws);
    _Float16* Wqh = (_Float16*)(ws + 8 * MB);
    _Float16* Wkh = (_Float16*)(ws + 10 * MB);
    _Float16* Wvh = (_Float16*)(ws + 12 * MB);
    _Float16* Woh = (_Float16*)(ws + 14 * MB);
    float*    Q0  = (float*)(ws + 16 * MB);
    float*    K0  = (float*)(ws + 32 * MB);
    float*    V0  = (float*)(ws + 48 * MB);
    _Float16* Kh  = (_Float16*)(ws);
    _Float16* Qh  = (_Float16*)(ws + 32 * MB);
    _Float16* Vt  = (_Float16*)(ws + 40 * MB);
    _Float16* Oh  = (_Float16*)(ws + 16 * MB);
    _Float16* Ol  = (_Float16*)(ws + 24 * MB);

    dim3 gB(256);
    dim3 gGemm(N / 128, M / 64);   // (8, 64)

    // convert inputs to f16
    cvt_kernel<<<(M * DD) / 2048, gB, 0, stream>>>(x, xh);
    wcvt_kernel<<<dim3((DD * DD) / 2048, 4), gB, 0, stream>>>(
        Wq, Wk, Wv, Wo, Wqh, Wkh, Wvh, Woh);

    // projections (single-product f16)
    gemm_f16<1><<<gGemm, gB, 0, stream>>>(xh, nullptr, Wqh, nullptr, Q0, M, N, K, 0);
    gemm_f16<1><<<gGemm, gB, 0, stream>>>(xh, nullptr, Wkh, nullptr, K0, M, N, K, 0);
    gemm_f16<1><<<gGemm, gB, 0, stream>>>(xh, nullptr, Wvh, nullptr, V0, M, N, K, 0);

    // normalize + layout transforms (buffer reuse is stream-ordered)
    const int nSeg = M * HH;  // 65536
    norm_kernel<<<nSeg / 4, gB, 0, stream>>>(K0, Kh);   // K0 dead after
    norm_kernel<<<nSeg / 4, gB, 0, stream>>>(Q0, Qh);   // writes into old K0
    vtrans_kernel<<<dim3(TT / 64, HH, BB), gB, 0, stream>>>(V0, Vt);

    // fused angular attention -> O split f16 hi/lo (into old Q0 region)
    attn_kernel<<<dim3(TT / 64, HH, BB), gB, 0, stream>>>(Qh, Kh, Vt, Oh, Ol);

    // output projection: (Oh + Ol) @ Woh^T + bo
    gemm_f16<2><<<gGemm, gB, 0, stream>>>(Oh, Ol, Woh, bo, out, M, N, K, 1);
}

// Round 3
// 374.251 us; speedup vs baseline: 1.0926x; 1.0926x over previous
//
#include <hip/hip_runtime.h>
#include <hip/hip_bf16.h>
#include <hip/hip_fp16.h>
#include <math.h>

// Problem constants
#define BB 2
#define TT 2048
#define DD 1024
#define HH 16
#define DK 64
#define KT 128            // keys per attention tile

typedef _Float16 f16x8 __attribute__((ext_vector_type(8)));
typedef __fp16 fp16x2 __attribute__((ext_vector_type(2)));
typedef __attribute__((ext_vector_type(4))) float f32x4;
typedef __attribute__((ext_vector_type(2))) float f32x2;

// async 16B global->LDS (lane i writes ldsbase + i*16)
static __device__ __forceinline__ void g2lds16(const void* g, void* l) {
    __builtin_amdgcn_global_load_lds(
        (const __attribute__((address_space(1))) unsigned int*)g,
        (__attribute__((address_space(3))) unsigned int*)l, 16, 0, 0);
}

// w = (1 - acos(clip(s,±0.999))/pi)^8 for a pair; rs accumulates pair sums.
// acos/pi via A&S 4.4.45 deg-3 (|err|<=5e-5 rad); reference's max(.,1e-6)
// is dead (clamp => t >= 0.0142). float2 ops lower to v_pk_* on gfx950.
// Magnitude-only clamp (abs folds into v_min modifier), packed 1-ax, and
// branch-free t = 0.5 + copysign(0.5 - uq, s).
static __device__ __forceinline__ f32x2 w8pair(f32x2 s, f32x2& rs) {
    f32x2 ax;
    ax.x = fminf(fabsf(s.x), 0.999f);
    ax.y = fminf(fabsf(s.y), 0.999f);
    f32x2 p = ax * -0.0059617f + 0.0236380f;
    p = p * ax + (-0.0675180f);
    p = p * ax + 0.49997851f;
    f32x2 om = 1.0f - ax;
    f32x2 u;
    u.x = sqrtf(om.x);
    u.y = sqrtf(om.y);
    f32x2 uq = u * p;
    f32x2 e = 0.5f - uq;
    f32x2 t;
    t.x = 0.5f + copysignf(e.x, s.x);
    t.y = 0.5f + copysignf(e.y, s.y);
    f32x2 t2 = t * t;
    f32x2 t4 = t2 * t2;
    f32x2 t8 = t4 * t4;
    rs += t8;
    return t8;
}
// one-instruction f16 pair pack (RTZ; |err|<=2^-11 rel, fine for W)
static __device__ __forceinline__ int packh2(f32x2 v) {
    union { fp16x2 h; int i; } u;
    u.h = __builtin_amdgcn_cvt_pkrtz(v.x, v.y);
    return u.i;
}

// ---------------------------------------------------------------------------
// fp32 -> f16 convert (n multiple of 2048; 8 elems/thread)
// ---------------------------------------------------------------------------
__global__ __launch_bounds__(256) void cvt_kernel(
    const float* __restrict__ src, _Float16* __restrict__ dst)
{
    const int i = (blockIdx.x * 256 + threadIdx.x) * 8;
    float4 a = *(const float4*)(src + i);
    float4 b = *(const float4*)(src + i + 4);
    union { _Float16 h[8]; int4 v; } u;
    u.h[0] = (_Float16)a.x; u.h[1] = (_Float16)a.y;
    u.h[2] = (_Float16)a.z; u.h[3] = (_Float16)a.w;
    u.h[4] = (_Float16)b.x; u.h[5] = (_Float16)b.y;
    u.h[6] = (_Float16)b.z; u.h[7] = (_Float16)b.w;
    *(int4*)(dst + i) = u.v;
}

// 4 weights at once (blockIdx.y selects)
__global__ __launch_bounds__(256) void wcvt_kernel(
    const float* __restrict__ s0, const float* __restrict__ s1,
    const float* __restrict__ s2, const float* __restrict__ s3,
    _Float16* __restrict__ d0, _Float16* __restrict__ d1,
    _Float16* __restrict__ d2, _Float16* __restrict__ d3)
{
    const float* s; _Float16* d;
    switch (blockIdx.y) {
        case 0: s = s0; d = d0; break;
        case 1: s = s1; d = d1; break;
        case 2: s = s2; d = d2; break;
        default: s = s3; d = d3; break;
    }
    const int i = (blockIdx.x * 256 + threadIdx.x) * 8;
    float4 a = *(const float4*)(s + i);
    float4 b = *(const float4*)(s + i + 4);
    union { _Float16 h[8]; int4 v; } u;
    u.h[0] = (_Float16)a.x; u.h[1] = (_Float16)a.y;
    u.h[2] = (_Float16)a.z; u.h[3] = (_Float16)a.w;
    u.h[4] = (_Float16)b.x; u.h[5] = (_Float16)b.y;
    u.h[6] = (_Float16)b.z; u.h[7] = (_Float16)b.w;
    *(int4*)(d + i) = u.v;
}

// ---------------------------------------------------------------------------
// Pure-f16 async MFMA GEMM: C[M,N] = (Ah [+ Al]) [M,K] @ B[N,K]^T (+bias).
// Inputs pre-converted f16. 64x128 tile, BK=64, 4 waves (2x2).
// LDS chunk-major [kc][row][8] so global_load_lds lane->slot is contiguous
// and frag ds_read_b128 is ~2-way bank aliased (free).
// NPROD=1: projections (single product). NPROD=2: + Al·B (Wo GEMM).
// ---------------------------------------------------------------------------
template<int NPROD>
__global__ __launch_bounds__(256) void gemm_f16(
    const _Float16* __restrict__ Ah_g, const _Float16* __restrict__ Al_g,
    const _Float16* __restrict__ B_g, const float* __restrict__ bias,
    float* __restrict__ C, int M, int N, int K, int hasBias)
{
    __shared__ _Float16 Ahs[8][64][8];    //  8 KB
    __shared__ _Float16 Als[8][64][8];    //  8 KB (unused traffic if NPROD=1)
    __shared__ _Float16 Bhs[8][128][8];   // 16 KB

    const int t    = threadIdx.x;
    const int m0   = blockIdx.y * 64;
    const int n0   = blockIdx.x * 128;
    const int lane = t & 63;
    const int w    = t >> 6;
    const int wm   = w >> 1;
    const int wn   = w & 1;
    const int l15  = lane & 15;
    const int quad = lane >> 4;

    f32x4 acc[2][4];
#pragma unroll
    for (int i = 0; i < 2; ++i)
#pragma unroll
        for (int j = 0; j < 4; ++j) acc[i][j] = (f32x4)0.f;

    for (int k0 = 0; k0 < K; k0 += 64) {
        __syncthreads();   // previous chunk's frag reads done
        // staging: wave w handles kc = 2w, 2w+1
#pragma unroll
        for (int i = 0; i < 2; ++i) {
            const int cc = w * 2 + i;
            g2lds16(Ah_g + (size_t)(m0 + lane) * K + k0 + cc * 8, &Ahs[cc][0][0]);
            if (NPROD == 2)
                g2lds16(Al_g + (size_t)(m0 + lane) * K + k0 + cc * 8, &Als[cc][0][0]);
#pragma unroll
            for (int half = 0; half < 2; ++half)
                g2lds16(B_g + (size_t)(n0 + half * 64 + lane) * K + k0 + cc * 8,
                        &Bhs[cc][half * 64][0]);
        }
        __syncthreads();   // vmcnt drained

#pragma unroll
        for (int kh = 0; kh < 2; ++kh) {
            f16x8 ah[2], bh[4];
#pragma unroll
            for (int tm = 0; tm < 2; ++tm)
                ah[tm] = *(const f16x8*)&Ahs[kh * 4 + quad][wm * 32 + tm * 16 + l15][0];
#pragma unroll
            for (int tn = 0; tn < 4; ++tn)
                bh[tn] = *(const f16x8*)&Bhs[kh * 4 + quad][wn * 64 + tn * 16 + l15][0];
#pragma unroll
            for (int tm = 0; tm < 2; ++tm)
#pragma unroll
                for (int tn = 0; tn < 4; ++tn)
                    acc[tm][tn] = __builtin_amdgcn_mfma_f32_16x16x32_f16(
                        ah[tm], bh[tn], acc[tm][tn], 0, 0, 0);
            if (NPROD == 2) {
                f16x8 al[2];
#pragma unroll
                for (int tm = 0; tm < 2; ++tm)
                    al[tm] = *(const f16x8*)&Als[kh * 4 + quad][wm * 32 + tm * 16 + l15][0];
#pragma unroll
                for (int tm = 0; tm < 2; ++tm)
#pragma unroll
                    for (int tn = 0; tn < 4; ++tn)
                        acc[tm][tn] = __builtin_amdgcn_mfma_f32_16x16x32_f16(
                            al[tm], bh[tn], acc[tm][tn], 0, 0, 0);
            }
        }
    }

#pragma unroll
    for (int tm = 0; tm < 2; ++tm)
#pragma unroll
        for (int tn = 0; tn < 4; ++tn) {
            const int col  = n0 + wn * 64 + tn * 16 + l15;
            const float bv = hasBias ? bias[col] : 0.f;
            const int rowb = m0 + wm * 32 + tm * 16 + quad * 4;
#pragma unroll
            for (int r = 0; r < 4; ++r)
                C[(size_t)(rowb + r) * N + col] = acc[tm][tn][r] + bv;
        }
}

// ---------------------------------------------------------------------------
// Normalize each 64-wide head segment; emit f16 at [b][h][t][dk].
// ---------------------------------------------------------------------------
__global__ __launch_bounds__(256) void norm_kernel(
    const float* __restrict__ X, _Float16* __restrict__ H)
{
    const int seg  = blockIdx.x * 4 + (threadIdx.x >> 6);
    const int lane = threadIdx.x & 63;
    const int row  = seg >> 4;   // b*T + t
    const int h    = seg & 15;
    float v = X[(size_t)row * DD + h * DK + lane];
    float s = v * v;
    s += __shfl_xor(s, 1);
    s += __shfl_xor(s, 2);
    s += __shfl_xor(s, 4);
    s += __shfl_xor(s, 8);
    s += __shfl_xor(s, 16);
    s += __shfl_xor(s, 32);
    float n = sqrtf(s);
    float vn = v / fmaxf(n, 1e-12f);
    const int b  = row >> 11;
    const int tt = row & 2047;
    H[((size_t)(b * HH + h) * TT + tt) * DK + lane] = (_Float16)vn;
}

// ---------------------------------------------------------------------------
// V -> f16 transposed [b][h][d][T].
// ---------------------------------------------------------------------------
__global__ __launch_bounds__(256) void vtrans_kernel(
    const float* __restrict__ V0, _Float16* __restrict__ Vt)
{
    __shared__ _Float16 Vtmp[64][72];
    const int t  = threadIdx.x;
    const int t0 = blockIdx.x * 64;
    const int h  = blockIdx.y;
    const int b  = blockIdx.z;

    {
        const int i  = t >> 2;            // token row 0..63
        const int jc = (t & 3) * 16;      // dim chunk
        const float* src = V0 + (size_t)(b * TT + t0 + i) * DD + h * DK + jc;
#pragma unroll
        for (int c = 0; c < 4; ++c) {
            float4 v = *(const float4*)(src + c * 4);
            Vtmp[jc + c * 4 + 0][i] = (_Float16)v.x;
            Vtmp[jc + c * 4 + 1][i] = (_Float16)v.y;
            Vtmp[jc + c * 4 + 2][i] = (_Float16)v.z;
            Vtmp[jc + c * 4 + 3][i] = (_Float16)v.w;
        }
    }
    __syncthreads();
    {
        const int d  = t >> 2;
        const int kc = (t & 3) * 16;
        _Float16* dst = Vt + ((size_t)((b * HH + h) * DK + d)) * TT + t0 + kc;
        *(int4*)(dst)     = *(const int4*)&Vtmp[d][kc];
        *(int4*)(dst + 8) = *(const int4*)&Vtmp[d][kc + 8];
    }
}

// ---------------------------------------------------------------------------
// MFMA angular attention v8 — all-f16. Grid (T/64, H, B), 256 threads.
// Combines the proven parts of v6 (160us) and v7:
//  - V staged in LDS (shared by 4 waves; bv at ds_read latency) but
//    DOUBLE-BUFFERED and issued a FULL TILE AHEAD, so the implicit
//    vmcnt(0) drain at the barrier hits loads issued ~2000 cycles
//    earlier: zero stall (v6 staged then immediately drained).
//  - K fragments from global into registers, prefetched one tile ahead
//    (v7's working half; K LDS staging + its ds_reads deleted).
//  - Q fragments in registers (v6).
//  - Ws single-buffered, 2 barriers/tile; neither barrier drains a
//    just-issued load.
// LDS 51456 B -> 3 blocks/CU; launch_bounds(256,3) keeps VGPR <= 170.
// ---------------------------------------------------------------------------
__global__ __launch_bounds__(256, 3) void attn_kernel(
    const _Float16* __restrict__ Qh_g, const _Float16* __restrict__ Kh_g,
    const _Float16* __restrict__ Vt_g,
    _Float16* __restrict__ Oh, _Float16* __restrict__ Ol)
{
    __shared__ _Float16 Vts[2][16][64][8]; // [buf][key-chunk][d][8] 32768 B
    __shared__ _Float16 Ws[64][136];       // [q][key]               17408 B
    __shared__ float Rbuf[4][64];          //                         1024 B
    __shared__ float Rfin[64];             //                          256 B

    const int t    = threadIdx.x;
    const int lane = t & 63;
    const int w    = t >> 6;
    const int l15  = lane & 15;
    const int quad = lane >> 4;
    const int q0   = blockIdx.x * 64;
    const int h    = blockIdx.y;
    const int b    = blockIdx.z;
    const size_t bh = (size_t)(b * HH + h);

    const _Float16* kh_g = Kh_g + bh * TT * DK;
    const _Float16* vt_g = Vt_g + bh * (size_t)DK * TT;

    // Q fragments in registers (loaded once, L2-served)
    f16x8 qf[4][2];
#pragma unroll
    for (int qt = 0; qt < 4; ++qt)
#pragma unroll
        for (int s = 0; s < 2; ++s)
            qf[qt][s] = *(const f16x8*)(Qh_g + (bh * TT + q0 + qt * 16 + l15) * DK
                                        + s * 32 + quad * 8);

    // K fragments for tile 0 (wave's 32 keys; 16B contiguous per lane)
    f16x8 kf[2][2], kfn[2][2];
#pragma unroll
    for (int s = 0; s < 2; ++s)
#pragma unroll
        for (int mt = 0; mt < 2; ++mt)
            kf[s][mt] = *(const f16x8*)(kh_g
                + (size_t)(w * 32 + mt * 16 + l15) * DK + s * 32 + quad * 8);

    // stage V tile 0 into buffer 0
#pragma unroll
    for (int j = 0; j < 4; ++j) {
        const int kc = w * 4 + j;
        g2lds16(vt_g + (size_t)lane * TT + kc * 8, &Vts[0][kc][0][0]);
    }

    f32x4 acc[4];    // O[16q x 64d] for q-tile w
#pragma unroll
    for (int j = 0; j < 4; ++j) acc[j] = (f32x4)0.f;
    f32x2 rs2[4];
#pragma unroll
    for (int j = 0; j < 4; ++j) rs2[j] = (f32x2)0.f;

    int vb = 0;
    for (int k0 = 0; k0 < TT; k0 += KT, vb ^= 1) {
        const int kn = k0 + KT;
        if (kn < TT) {
            // stage V[t+1] into the other buffer (consumed after NEXT BAR1)
#pragma unroll
            for (int j = 0; j < 4; ++j) {
                const int kc = w * 4 + j;
                g2lds16(vt_g + (size_t)lane * TT + kn + kc * 8,
                        &Vts[vb ^ 1][kc][0][0]);
            }
            // prefetch K fragments for tile t+1
#pragma unroll
            for (int s = 0; s < 2; ++s)
#pragma unroll
                for (int mt = 0; mt < 2; ++mt)
                    kfn[s][mt] = *(const f16x8*)(kh_g
                        + (size_t)(kn + w * 32 + mt * 16 + l15) * DK
                        + s * 32 + quad * 8);
        }

        // Phase A: S^T for wave's 32 keys x 64 q, transform, write Ws
#pragma unroll
        for (int qt = 0; qt < 4; ++qt) {
            f32x4 c_[2];
            c_[0] = (f32x4)0.f;
            c_[1] = (f32x4)0.f;
#pragma unroll
            for (int s = 0; s < 2; ++s) {
#pragma unroll
                for (int mt = 0; mt < 2; ++mt)
                    c_[mt] = __builtin_amdgcn_mfma_f32_16x16x32_f16(
                        kf[s][mt], qf[qt][s], c_[mt], 0, 0, 0);
            }
#pragma unroll
            for (int mt = 0; mt < 2; ++mt) {
                f32x2 p01, p23;
                p01.x = c_[mt][0]; p01.y = c_[mt][1];
                p23.x = c_[mt][2]; p23.y = c_[mt][3];
                f32x2 w01 = w8pair(p01, rs2[qt]);
                f32x2 w23 = w8pair(p23, rs2[qt]);
                int2 pk;
                pk.x = packh2(w01);
                pk.y = packh2(w23);
                *(int2*)&Ws[qt * 16 + l15][w * 32 + mt * 16 + quad * 4] = pk;
            }
        }
        __syncthreads();   // BAR1: Ws ready; V[t] (staged last iter) arrived

        // Phase B: PV for q-tile w over all 128 keys from Vts[vb]
#pragma unroll
        for (int kstep = 0; kstep < 4; ++kstep) {
            f16x8 av = *(const f16x8*)&Ws[16 * w + l15][kstep * 32 + quad * 8];
#pragma unroll
            for (int nd = 0; nd < 4; ++nd) {
                f16x8 bv = *(const f16x8*)&Vts[vb][kstep * 4 + quad][nd * 16 + l15][0];
                acc[nd] = __builtin_amdgcn_mfma_f32_16x16x32_f16(
                    av, bv, acc[nd], 0, 0, 0);
            }
        }
        __syncthreads();   // BAR2: Ws reads done (next A rewrites); Vts[vb^1]
                           // reads of t-1 done before t's g2lds rewrote it

        // roll K prefetch
#pragma unroll
        for (int s = 0; s < 2; ++s)
#pragma unroll
            for (int mt = 0; mt < 2; ++mt)
                kf[s][mt] = kfn[s][mt];
    }

    // rowsum: rs2[qt] covers q = qt*16+l15 over wave's keys
#pragma unroll
    for (int qt = 0; qt < 4; ++qt) {
        float pr = rs2[qt].x + rs2[qt].y;
        pr += __shfl_xor(pr, 16);
        pr += __shfl_xor(pr, 32);
        if (quad == 0) Rbuf[w][qt * 16 + l15] = pr;
    }
    __syncthreads();
    if (t < 64) {
        float s = Rbuf[0][t] + Rbuf[1][t] + Rbuf[2][t] + Rbuf[3][t];
        Rfin[t] = 1.f / (s + 1e-6f);
    }
    __syncthreads();

    // store: O split hi/lo f16 (feeds the 2-product Wo GEMM)
#pragma unroll
    for (int r = 0; r < 4; ++r) {
        const int q = 16 * w + quad * 4 + r;
        const float inv = Rfin[q];
        const size_t base = (size_t)(b * TT + q0 + q) * DD + h * DK + l15;
#pragma unroll
        for (int nd = 0; nd < 4; ++nd) {
            float v = acc[nd][r] * inv;
            _Float16 hv = (_Float16)v;
            Oh[base + nd * 16] = hv;
            Ol[base + nd * 16] = (_Float16)(v - (float)hv);
        }
    }
}

// ---------------------------------------------------------------------------
extern "C" void kernel_launch(void* const* d_in, const int* in_sizes, int n_in,
                              void* d_out, int out_size, void* d_ws, size_t ws_size,
                              hipStream_t stream)
{
    const float* x  = (const float*)d_in[0];
    const float* Wq = (const float*)d_in[1];
    const float* Wk = (const float*)d_in[2];
    const float* Wv = (const float*)d_in[3];
    const float* Wo = (const float*)d_in[4];
    const float* bo = (const float*)d_in[5];
    float* out = (float*)d_out;

    const int M = BB * TT;   // 4096
    const int N = DD;
    const int K = DD;

    const size_t MB = 1024 * 1024;
    char* ws = (char*)d_ws;
    // [0,8):   xh f16                -> Kh f16 (after projections)
    // [8,16):  Wqh,Wkh,Wvh,Woh f16 (2 MB each; Woh persists)
    // [16,32): Q0 fp32               -> Oh [16,24) + Ol [24,32) (after norm Q)
    // [32,48): K0 fp32               -> Qh [32,40) + Vt [40,48) (after norm K)
    // [48,64): V0 fp32
    _Float16* xh  = (_Float16*)(ws);
    _Float16* Wqh = (_Float16*)(ws + 8 * MB);
    _Float16* Wkh = (_Float16*)(ws + 10 * MB);
    _Float16* Wvh = (_Float16*)(ws + 12 * MB);
    _Float16* Woh = (_Float16*)(ws + 14 * MB);
    float*    Q0  = (float*)(ws + 16 * MB);
    float*    K0  = (float*)(ws + 32 * MB);
    float*    V0  = (float*)(ws + 48 * MB);
    _Float16* Kh  = (_Float16*)(ws);
    _Float16* Qh  = (_Float16*)(ws + 32 * MB);
    _Float16* Vt  = (_Float16*)(ws + 40 * MB);
    _Float16* Oh  = (_Float16*)(ws + 16 * MB);
    _Float16* Ol  = (_Float16*)(ws + 24 * MB);

    dim3 gB(256);
    dim3 gGemm(N / 128, M / 64);   // (8, 64)

    // convert inputs to f16
    cvt_kernel<<<(M * DD) / 2048, gB, 0, stream>>>(x, xh);
    wcvt_kernel<<<dim3((DD * DD) / 2048, 4), gB, 0, stream>>>(
        Wq, Wk, Wv, Wo, Wqh, Wkh, Wvh, Woh);

    // projections (single-product f16)
    gemm_f16<1><<<gGemm, gB, 0, stream>>>(xh, nullptr, Wqh, nullptr, Q0, M, N, K, 0);
    gemm_f16<1><<<gGemm, gB, 0, stream>>>(xh, nullptr, Wkh, nullptr, K0, M, N, K, 0);
    gemm_f16<1><<<gGemm, gB, 0, stream>>>(xh, nullptr, Wvh, nullptr, V0, M, N, K, 0);

    // normalize + layout transforms (buffer reuse is stream-ordered)
    const int nSeg = M * HH;  // 65536
    norm_kernel<<<nSeg / 4, gB, 0, stream>>>(K0, Kh);   // K0 dead after
    norm_kernel<<<nSeg / 4, gB, 0, stream>>>(Q0, Qh);   // writes into old K0
    vtrans_kernel<<<dim3(TT / 64, HH, BB), gB, 0, stream>>>(V0, Vt);

    // fused angular attention -> O split f16 hi/lo (into old Q0 region)
    attn_kernel<<<dim3(TT / 64, HH, BB), gB, 0, stream>>>(Qh, Kh, Vt, Oh, Ol);

    // output projection: (Oh + Ol) @ Woh^T + bo
    gemm_f16<2><<<gGemm, gB, 0, stream>>>(Oh, Ol, Woh, bo, out, M, N, K, 1);
}

// Round 4
// 349.880 us; speedup vs baseline: 1.1687x; 1.0697x over previous
//
#include <hip/hip_runtime.h>
#include <hip/hip_bf16.h>
#include <hip/hip_fp16.h>
#include <math.h>

// Problem constants
#define BB 2
#define TT 2048
#define DD 1024
#define HH 16
#define DK 64
#define KT 128            // keys per attention tile

typedef _Float16 f16x8 __attribute__((ext_vector_type(8)));
typedef __fp16 fp16x2 __attribute__((ext_vector_type(2)));
typedef __attribute__((ext_vector_type(4))) float f32x4;
typedef __attribute__((ext_vector_type(2))) float f32x2;

// async 16B global->LDS (lane i writes ldsbase + i*16)
static __device__ __forceinline__ void g2lds16(const void* g, void* l) {
    __builtin_amdgcn_global_load_lds(
        (const __attribute__((address_space(1))) unsigned int*)g,
        (__attribute__((address_space(3))) unsigned int*)l, 16, 0, 0);
}

// w = (1 - acos(clip(s,±0.999))/pi)^8 for a pair; rs accumulates pair sums.
// acos/pi via A&S 4.4.45 deg-3 (|err|<=5e-5 rad); reference's max(.,1e-6)
// is dead (clamp => t >= 0.0142). float2 ops lower to v_pk_* on gfx950.
// Magnitude-only clamp (abs folds into v_min modifier), packed 1-ax, and
// branch-free t = 0.5 + copysign(0.5 - uq, s).
static __device__ __forceinline__ f32x2 w8pair(f32x2 s, f32x2& rs) {
    f32x2 ax;
    ax.x = fminf(fabsf(s.x), 0.999f);
    ax.y = fminf(fabsf(s.y), 0.999f);
    f32x2 p = ax * -0.0059617f + 0.0236380f;
    p = p * ax + (-0.0675180f);
    p = p * ax + 0.49997851f;
    f32x2 om = 1.0f - ax;
    f32x2 u;
    u.x = sqrtf(om.x);
    u.y = sqrtf(om.y);
    f32x2 uq = u * p;
    f32x2 e = 0.5f - uq;
    f32x2 t;
    t.x = 0.5f + copysignf(e.x, s.x);
    t.y = 0.5f + copysignf(e.y, s.y);
    f32x2 t2 = t * t;
    f32x2 t4 = t2 * t2;
    f32x2 t8 = t4 * t4;
    rs += t8;
    return t8;
}
// one-instruction f16 pair pack (RTZ; |err|<=2^-11 rel, fine for W)
static __device__ __forceinline__ int packh2(f32x2 v) {
    union { fp16x2 h; int i; } u;
    u.h = __builtin_amdgcn_cvt_pkrtz(v.x, v.y);
    return u.i;
}

// ---------------------------------------------------------------------------
// fp32 -> f16 convert (n multiple of 2048; 8 elems/thread)
// ---------------------------------------------------------------------------
__global__ __launch_bounds__(256) void cvt_kernel(
    const float* __restrict__ src, _Float16* __restrict__ dst)
{
    const int i = (blockIdx.x * 256 + threadIdx.x) * 8;
    float4 a = *(const float4*)(src + i);
    float4 b = *(const float4*)(src + i + 4);
    union { _Float16 h[8]; int4 v; } u;
    u.h[0] = (_Float16)a.x; u.h[1] = (_Float16)a.y;
    u.h[2] = (_Float16)a.z; u.h[3] = (_Float16)a.w;
    u.h[4] = (_Float16)b.x; u.h[5] = (_Float16)b.y;
    u.h[6] = (_Float16)b.z; u.h[7] = (_Float16)b.w;
    *(int4*)(dst + i) = u.v;
}

// 4 weights at once (blockIdx.y selects)
__global__ __launch_bounds__(256) void wcvt_kernel(
    const float* __restrict__ s0, const float* __restrict__ s1,
    const float* __restrict__ s2, const float* __restrict__ s3,
    _Float16* __restrict__ d0, _Float16* __restrict__ d1,
    _Float16* __restrict__ d2, _Float16* __restrict__ d3)
{
    const float* s; _Float16* d;
    switch (blockIdx.y) {
        case 0: s = s0; d = d0; break;
        case 1: s = s1; d = d1; break;
        case 2: s = s2; d = d2; break;
        default: s = s3; d = d3; break;
    }
    const int i = (blockIdx.x * 256 + threadIdx.x) * 8;
    float4 a = *(const float4*)(s + i);
    float4 b = *(const float4*)(s + i + 4);
    union { _Float16 h[8]; int4 v; } u;
    u.h[0] = (_Float16)a.x; u.h[1] = (_Float16)a.y;
    u.h[2] = (_Float16)a.z; u.h[3] = (_Float16)a.w;
    u.h[4] = (_Float16)b.x; u.h[5] = (_Float16)b.y;
    u.h[6] = (_Float16)b.z; u.h[7] = (_Float16)b.w;
    *(int4*)(d + i) = u.v;
}

// ---------------------------------------------------------------------------
// m97-class f16 MFMA GEMM: 128x128 tile, BK=64, 4 waves (2x2, 64x64 each).
// C[M, 3*1024 or 1024] = (Ah [+ Al]) @ B^T (+bias); B rows = output cols.
// Output column segment (n0>>10) selects C0/C1/C2 (fused QKV projections
// write Q0/K0/V0 from one launch; Wo GEMM uses seg 0 only).
// Chunk-major LDS [kc][row][8]: g2lds16 lane->slot contiguous, frag
// ds_read_b128 2-way bank aliased. 32 MFMA/wave/chunk (NPROD=1).
// 1D grid + XCD-bijective swizzle (nwg % 8 == 0): consecutive blocks on an
// XCD share the A-panel (L2-resident 256 KB).
// ---------------------------------------------------------------------------
template<int NPROD>
__global__ __launch_bounds__(256, NPROD == 1 ? 3 : 2) void gemm_f16_128(
    const _Float16* __restrict__ Ah_g, const _Float16* __restrict__ Al_g,
    const _Float16* __restrict__ B_g, const float* __restrict__ bias,
    float* __restrict__ C0, float* __restrict__ C1, float* __restrict__ C2,
    int nbx, int K, int hasBias)
{
    __shared__ _Float16 Ahs[8][128][8];                    // 16 KB
    __shared__ _Float16 Bhs[8][128][8];                    // 16 KB
    __shared__ _Float16 Als[NPROD == 2 ? 8 : 1][128][8];   // 16 KB / 2 KB

    // XCD-bijective swizzle (nwg multiple of 8)
    const int nwg  = gridDim.x;
    const int wgid = blockIdx.x;
    const int cpx  = nwg >> 3;
    const int swz  = (wgid & 7) * cpx + (wgid >> 3);
    const int by   = swz / nbx;
    const int bx   = swz - by * nbx;

    const int t    = threadIdx.x;
    const int m0   = by * 128;
    const int n0g  = bx * 128;
    const int seg  = n0g >> 10;
    const int n0   = n0g & 1023;
    float* __restrict__ C = (seg == 0) ? C0 : (seg == 1) ? C1 : C2;

    const int lane = t & 63;
    const int w    = t >> 6;
    const int wm   = w >> 1;
    const int wn   = w & 1;
    const int l15  = lane & 15;
    const int quad = lane >> 4;

    f32x4 acc[4][4];
#pragma unroll
    for (int i = 0; i < 4; ++i)
#pragma unroll
        for (int j = 0; j < 4; ++j) acc[i][j] = (f32x4)0.f;

    for (int k0 = 0; k0 < K; k0 += 64) {
        __syncthreads();   // previous chunk's frag reads done
        // staging: wave w handles chunks cc = 2w, 2w+1 (128 rows = 2 halves)
#pragma unroll
        for (int i = 0; i < 2; ++i) {
            const int cc = w * 2 + i;
#pragma unroll
            for (int half = 0; half < 2; ++half) {
                g2lds16(Ah_g + (size_t)(m0 + half * 64 + lane) * K + k0 + cc * 8,
                        &Ahs[cc][half * 64][0]);
                if (NPROD == 2)
                    g2lds16(Al_g + (size_t)(m0 + half * 64 + lane) * K + k0 + cc * 8,
                            &Als[cc][half * 64][0]);
                g2lds16(B_g + (size_t)(n0g + half * 64 + lane) * K + k0 + cc * 8,
                        &Bhs[cc][half * 64][0]);
            }
        }
        __syncthreads();   // vmcnt drained

#pragma unroll
        for (int kh = 0; kh < 2; ++kh) {
            f16x8 ah[4], bh[4];
#pragma unroll
            for (int tm = 0; tm < 4; ++tm)
                ah[tm] = *(const f16x8*)&Ahs[kh * 4 + quad][wm * 64 + tm * 16 + l15][0];
#pragma unroll
            for (int tn = 0; tn < 4; ++tn)
                bh[tn] = *(const f16x8*)&Bhs[kh * 4 + quad][wn * 64 + tn * 16 + l15][0];
#pragma unroll
            for (int tm = 0; tm < 4; ++tm)
#pragma unroll
                for (int tn = 0; tn < 4; ++tn)
                    acc[tm][tn] = __builtin_amdgcn_mfma_f32_16x16x32_f16(
                        ah[tm], bh[tn], acc[tm][tn], 0, 0, 0);
            if (NPROD == 2) {
                f16x8 al[4];
#pragma unroll
                for (int tm = 0; tm < 4; ++tm)
                    al[tm] = *(const f16x8*)&Als[kh * 4 + quad][wm * 64 + tm * 16 + l15][0];
#pragma unroll
                for (int tm = 0; tm < 4; ++tm)
#pragma unroll
                    for (int tn = 0; tn < 4; ++tn)
                        acc[tm][tn] = __builtin_amdgcn_mfma_f32_16x16x32_f16(
                            al[tm], bh[tn], acc[tm][tn], 0, 0, 0);
            }
        }
    }

#pragma unroll
    for (int tm = 0; tm < 4; ++tm)
#pragma unroll
        for (int tn = 0; tn < 4; ++tn) {
            const int col  = n0 + wn * 64 + tn * 16 + l15;
            const float bv = hasBias ? bias[col] : 0.f;
            const int rowb = m0 + wm * 64 + tm * 16 + quad * 4;
#pragma unroll
            for (int r = 0; r < 4; ++r)
                C[(size_t)(rowb + r) * 1024 + col] = acc[tm][tn][r] + bv;
        }
}

// ---------------------------------------------------------------------------
// Normalize each 64-wide head segment; emit f16 at [b][h][t][dk].
// ---------------------------------------------------------------------------
__global__ __launch_bounds__(256) void norm_kernel(
    const float* __restrict__ X, _Float16* __restrict__ H)
{
    const int seg  = blockIdx.x * 4 + (threadIdx.x >> 6);
    const int lane = threadIdx.x & 63;
    const int row  = seg >> 4;   // b*T + t
    const int h    = seg & 15;
    float v = X[(size_t)row * DD + h * DK + lane];
    float s = v * v;
    s += __shfl_xor(s, 1);
    s += __shfl_xor(s, 2);
    s += __shfl_xor(s, 4);
    s += __shfl_xor(s, 8);
    s += __shfl_xor(s, 16);
    s += __shfl_xor(s, 32);
    float n = sqrtf(s);
    float vn = v / fmaxf(n, 1e-12f);
    const int b  = row >> 11;
    const int tt = row & 2047;
    H[((size_t)(b * HH + h) * TT + tt) * DK + lane] = (_Float16)vn;
}

// ---------------------------------------------------------------------------
// V -> f16 transposed [b][h][d][T].
// ---------------------------------------------------------------------------
__global__ __launch_bounds__(256) void vtrans_kernel(
    const float* __restrict__ V0, _Float16* __restrict__ Vt)
{
    __shared__ _Float16 Vtmp[64][72];
    const int t  = threadIdx.x;
    const int t0 = blockIdx.x * 64;
    const int h  = blockIdx.y;
    const int b  = blockIdx.z;

    {
        const int i  = t >> 2;            // token row 0..63
        const int jc = (t & 3) * 16;      // dim chunk
        const float* src = V0 + (size_t)(b * TT + t0 + i) * DD + h * DK + jc;
#pragma unroll
        for (int c = 0; c < 4; ++c) {
            float4 v = *(const float4*)(src + c * 4);
            Vtmp[jc + c * 4 + 0][i] = (_Float16)v.x;
            Vtmp[jc + c * 4 + 1][i] = (_Float16)v.y;
            Vtmp[jc + c * 4 + 2][i] = (_Float16)v.z;
            Vtmp[jc + c * 4 + 3][i] = (_Float16)v.w;
        }
    }
    __syncthreads();
    {
        const int d  = t >> 2;
        const int kc = (t & 3) * 16;
        _Float16* dst = Vt + ((size_t)((b * HH + h) * DK + d)) * TT + t0 + kc;
        *(int4*)(dst)     = *(const int4*)&Vtmp[d][kc];
        *(int4*)(dst + 8) = *(const int4*)&Vtmp[d][kc + 8];
    }
}

// ---------------------------------------------------------------------------
// MFMA angular attention v8 — all-f16. Grid (T/64, H, B), 256 threads.
//  - V staged in LDS (shared by 4 waves), double-buffered, issued a full
//    tile ahead so the barrier's vmcnt(0) drain hits arrived loads.
//  - K fragments from global into registers, prefetched one tile ahead.
//  - Q fragments in registers.
//  - Ws single-buffered, 2 barriers/tile; neither drains a fresh load.
// LDS 51456 B -> 3 blocks/CU.
// ---------------------------------------------------------------------------
__global__ __launch_bounds__(256, 3) void attn_kernel(
    const _Float16* __restrict__ Qh_g, const _Float16* __restrict__ Kh_g,
    const _Float16* __restrict__ Vt_g,
    _Float16* __restrict__ Oh, _Float16* __restrict__ Ol)
{
    __shared__ _Float16 Vts[2][16][64][8]; // [buf][key-chunk][d][8] 32768 B
    __shared__ _Float16 Ws[64][136];       // [q][key]               17408 B
    __shared__ float Rbuf[4][64];          //                         1024 B
    __shared__ float Rfin[64];             //                          256 B

    const int t    = threadIdx.x;
    const int lane = t & 63;
    const int w    = t >> 6;
    const int l15  = lane & 15;
    const int quad = lane >> 4;
    const int q0   = blockIdx.x * 64;
    const int h    = blockIdx.y;
    const int b    = blockIdx.z;
    const size_t bh = (size_t)(b * HH + h);

    const _Float16* kh_g = Kh_g + bh * TT * DK;
    const _Float16* vt_g = Vt_g + bh * (size_t)DK * TT;

    // Q fragments in registers (loaded once, L2-served)
    f16x8 qf[4][2];
#pragma unroll
    for (int qt = 0; qt < 4; ++qt)
#pragma unroll
        for (int s = 0; s < 2; ++s)
            qf[qt][s] = *(const f16x8*)(Qh_g + (bh * TT + q0 + qt * 16 + l15) * DK
                                        + s * 32 + quad * 8);

    // K fragments for tile 0 (wave's 32 keys; 16B contiguous per lane)
    f16x8 kf[2][2], kfn[2][2];
#pragma unroll
    for (int s = 0; s < 2; ++s)
#pragma unroll
        for (int mt = 0; mt < 2; ++mt)
            kf[s][mt] = *(const f16x8*)(kh_g
                + (size_t)(w * 32 + mt * 16 + l15) * DK + s * 32 + quad * 8);

    // stage V tile 0 into buffer 0
#pragma unroll
    for (int j = 0; j < 4; ++j) {
        const int kc = w * 4 + j;
        g2lds16(vt_g + (size_t)lane * TT + kc * 8, &Vts[0][kc][0][0]);
    }

    f32x4 acc[4];    // O[16q x 64d] for q-tile w
#pragma unroll
    for (int j = 0; j < 4; ++j) acc[j] = (f32x4)0.f;
    f32x2 rs2[4];
#pragma unroll
    for (int j = 0; j < 4; ++j) rs2[j] = (f32x2)0.f;

    int vb = 0;
    for (int k0 = 0; k0 < TT; k0 += KT, vb ^= 1) {
        const int kn = k0 + KT;
        if (kn < TT) {
            // stage V[t+1] into the other buffer (consumed after NEXT BAR1)
#pragma unroll
            for (int j = 0; j < 4; ++j) {
                const int kc = w * 4 + j;
                g2lds16(vt_g + (size_t)lane * TT + kn + kc * 8,
                        &Vts[vb ^ 1][kc][0][0]);
            }
            // prefetch K fragments for tile t+1
#pragma unroll
            for (int s = 0; s < 2; ++s)
#pragma unroll
                for (int mt = 0; mt < 2; ++mt)
                    kfn[s][mt] = *(const f16x8*)(kh_g
                        + (size_t)(kn + w * 32 + mt * 16 + l15) * DK
                        + s * 32 + quad * 8);
        }

        // Phase A: S^T for wave's 32 keys x 64 q, transform, write Ws
#pragma unroll
        for (int qt = 0; qt < 4; ++qt) {
            f32x4 c_[2];
            c_[0] = (f32x4)0.f;
            c_[1] = (f32x4)0.f;
#pragma unroll
            for (int s = 0; s < 2; ++s) {
#pragma unroll
                for (int mt = 0; mt < 2; ++mt)
                    c_[mt] = __builtin_amdgcn_mfma_f32_16x16x32_f16(
                        kf[s][mt], qf[qt][s], c_[mt], 0, 0, 0);
            }
#pragma unroll
            for (int mt = 0; mt < 2; ++mt) {
                f32x2 p01, p23;
                p01.x = c_[mt][0]; p01.y = c_[mt][1];
                p23.x = c_[mt][2]; p23.y = c_[mt][3];
                f32x2 w01 = w8pair(p01, rs2[qt]);
                f32x2 w23 = w8pair(p23, rs2[qt]);
                int2 pk;
                pk.x = packh2(w01);
                pk.y = packh2(w23);
                *(int2*)&Ws[qt * 16 + l15][w * 32 + mt * 16 + quad * 4] = pk;
            }
        }
        __syncthreads();   // BAR1: Ws ready; V[t] (staged last iter) arrived

        // Phase B: PV for q-tile w over all 128 keys from Vts[vb]
#pragma unroll
        for (int kstep = 0; kstep < 4; ++kstep) {
            f16x8 av = *(const f16x8*)&Ws[16 * w + l15][kstep * 32 + quad * 8];
#pragma unroll
            for (int nd = 0; nd < 4; ++nd) {
                f16x8 bv = *(const f16x8*)&Vts[vb][kstep * 4 + quad][nd * 16 + l15][0];
                acc[nd] = __builtin_amdgcn_mfma_f32_16x16x32_f16(
                    av, bv, acc[nd], 0, 0, 0);
            }
        }
        __syncthreads();   // BAR2: Ws reads done; Vts[vb^1] reads of t-1 done

        // roll K prefetch
#pragma unroll
        for (int s = 0; s < 2; ++s)
#pragma unroll
            for (int mt = 0; mt < 2; ++mt)
                kf[s][mt] = kfn[s][mt];
    }

    // rowsum: rs2[qt] covers q = qt*16+l15 over wave's keys
#pragma unroll
    for (int qt = 0; qt < 4; ++qt) {
        float pr = rs2[qt].x + rs2[qt].y;
        pr += __shfl_xor(pr, 16);
        pr += __shfl_xor(pr, 32);
        if (quad == 0) Rbuf[w][qt * 16 + l15] = pr;
    }
    __syncthreads();
    if (t < 64) {
        float s = Rbuf[0][t] + Rbuf[1][t] + Rbuf[2][t] + Rbuf[3][t];
        Rfin[t] = 1.f / (s + 1e-6f);
    }
    __syncthreads();

    // store: O split hi/lo f16 (feeds the 2-product Wo GEMM)
#pragma unroll
    for (int r = 0; r < 4; ++r) {
        const int q = 16 * w + quad * 4 + r;
        const float inv = Rfin[q];
        const size_t base = (size_t)(b * TT + q0 + q) * DD + h * DK + l15;
#pragma unroll
        for (int nd = 0; nd < 4; ++nd) {
            float v = acc[nd][r] * inv;
            _Float16 hv = (_Float16)v;
            Oh[base + nd * 16] = hv;
            Ol[base + nd * 16] = (_Float16)(v - (float)hv);
        }
    }
}

// ---------------------------------------------------------------------------
extern "C" void kernel_launch(void* const* d_in, const int* in_sizes, int n_in,
                              void* d_out, int out_size, void* d_ws, size_t ws_size,
                              hipStream_t stream)
{
    const float* x  = (const float*)d_in[0];
    const float* Wq = (const float*)d_in[1];
    const float* Wk = (const float*)d_in[2];
    const float* Wv = (const float*)d_in[3];
    const float* Wo = (const float*)d_in[4];
    const float* bo = (const float*)d_in[5];
    float* out = (float*)d_out;

    const int M = BB * TT;   // 4096
    const int K = DD;

    const size_t MB = 1024 * 1024;
    char* ws = (char*)d_ws;
    // [0,8):   xh f16                -> Kh f16 (after projections)
    // [8,14):  W3h f16 = [Wq;Wk;Wv] rows (3072x1024, 6 MB, contiguous)
    // [14,16): Woh f16 (persists)
    // [16,32): Q0 fp32               -> Oh [16,24) + Ol [24,32) (after norm Q)
    // [32,48): K0 fp32               -> Qh [32,40) + Vt [40,48) (after norm K)
    // [48,64): V0 fp32
    _Float16* xh  = (_Float16*)(ws);
    _Float16* W3h = (_Float16*)(ws + 8 * MB);
    _Float16* Wqh = W3h;                              // rows    0..1023
    _Float16* Wkh = (_Float16*)(ws + 10 * MB);        // rows 1024..2047
    _Float16* Wvh = (_Float16*)(ws + 12 * MB);        // rows 2048..3071
    _Float16* Woh = (_Float16*)(ws + 14 * MB);
    float*    Q0  = (float*)(ws + 16 * MB);
    float*    K0  = (float*)(ws + 32 * MB);
    float*    V0  = (float*)(ws + 48 * MB);
    _Float16* Kh  = (_Float16*)(ws);
    _Float16* Qh  = (_Float16*)(ws + 32 * MB);
    _Float16* Vt  = (_Float16*)(ws + 40 * MB);
    _Float16* Oh  = (_Float16*)(ws + 16 * MB);
    _Float16* Ol  = (_Float16*)(ws + 24 * MB);

    dim3 gB(256);

    // convert inputs to f16
    cvt_kernel<<<(M * DD) / 2048, gB, 0, stream>>>(x, xh);
    wcvt_kernel<<<dim3((DD * DD) / 2048, 4), gB, 0, stream>>>(
        Wq, Wk, Wv, Wo, Wqh, Wkh, Wvh, Woh);

    // fused QKV projection: one 128x128-tile GEMM over B = [Wq;Wk;Wv]
    // (3072 output cols); segment n0>>10 routes to Q0/K0/V0.
    {
        const int nbx = 3072 / 128;              // 24
        const int nby = M / 128;                 // 32
        gemm_f16_128<1><<<nbx * nby, gB, 0, stream>>>(
            xh, nullptr, W3h, nullptr, Q0, K0, V0, nbx, K, 0);
    }

    // normalize + layout transforms (buffer reuse is stream-ordered)
    const int nSeg = M * HH;  // 65536
    norm_kernel<<<nSeg / 4, gB, 0, stream>>>(K0, Kh);   // K0 dead after
    norm_kernel<<<nSeg / 4, gB, 0, stream>>>(Q0, Qh);   // writes into old K0
    vtrans_kernel<<<dim3(TT / 64, HH, BB), gB, 0, stream>>>(V0, Vt);

    // fused angular attention -> O split f16 hi/lo (into old Q0 region)
    attn_kernel<<<dim3(TT / 64, HH, BB), gB, 0, stream>>>(Qh, Kh, Vt, Oh, Ol);

    // output projection: (Oh + Ol) @ Woh^T + bo
    {
        const int nbx = 1024 / 128;              // 8
        const int nby = M / 128;                 // 32
        gemm_f16_128<2><<<nbx * nby, gB, 0, stream>>>(
            Oh, Ol, Woh, bo, out, nullptr, nullptr, nbx, K, 1);
    }
}

// Round 5
// 326.001 us; speedup vs baseline: 1.2543x; 1.0732x over previous
//
#include <hip/hip_runtime.h>
#include <hip/hip_bf16.h>
#include <hip/hip_fp16.h>
#include <math.h>

// Problem constants
#define BB 2
#define TT 2048
#define DD 1024
#define HH 16
#define DK 64
#define KT 128            // keys per attention tile

typedef _Float16 f16x8 __attribute__((ext_vector_type(8)));
typedef __fp16 fp16x2 __attribute__((ext_vector_type(2)));
typedef __attribute__((ext_vector_type(4))) float f32x4;
typedef __attribute__((ext_vector_type(2))) float f32x2;

// async 16B global->LDS (lane i writes ldsbase + i*16)
static __device__ __forceinline__ void g2lds16(const void* g, void* l) {
    __builtin_amdgcn_global_load_lds(
        (const __attribute__((address_space(1))) unsigned int*)g,
        (__attribute__((address_space(3))) unsigned int*)l, 16, 0, 0);
}

// w = (1 - acos(clip(s,±0.999))/pi)^8 for a pair; rs accumulates pair sums.
// acos/pi via A&S 4.4.45 deg-3 (|err|<=5e-5 rad); reference's max(.,1e-6)
// is dead (clamp => t >= 0.0142). float2 ops lower to v_pk_* on gfx950.
static __device__ __forceinline__ f32x2 w8pair(f32x2 s, f32x2& rs) {
    f32x2 ax;
    ax.x = fminf(fabsf(s.x), 0.999f);
    ax.y = fminf(fabsf(s.y), 0.999f);
    f32x2 p = ax * -0.0059617f + 0.0236380f;
    p = p * ax + (-0.0675180f);
    p = p * ax + 0.49997851f;
    f32x2 om = 1.0f - ax;
    f32x2 u;
    u.x = sqrtf(om.x);
    u.y = sqrtf(om.y);
    f32x2 uq = u * p;
    f32x2 e = 0.5f - uq;
    f32x2 t;
    t.x = 0.5f + copysignf(e.x, s.x);
    t.y = 0.5f + copysignf(e.y, s.y);
    f32x2 t2 = t * t;
    f32x2 t4 = t2 * t2;
    f32x2 t8 = t4 * t4;
    rs += t8;
    return t8;
}
// one-instruction f16 pair pack (RTZ; |err|<=2^-11 rel, fine for W)
static __device__ __forceinline__ int packh2(f32x2 v) {
    union { fp16x2 h; int i; } u;
    u.h = __builtin_amdgcn_cvt_pkrtz(v.x, v.y);
    return u.i;
}

// ---------------------------------------------------------------------------
// One-launch fp32 -> f16 convert for x + all 4 weight matrices.
// bid < 2048: x -> xh. Else weights: Wq/Wk/Wv -> W3h rows (contiguous),
// Wo -> Woh. 8 elems/thread.
// ---------------------------------------------------------------------------
__global__ __launch_bounds__(256) void cvtall_kernel(
    const float* __restrict__ x,  const float* __restrict__ Wq,
    const float* __restrict__ Wk, const float* __restrict__ Wv,
    const float* __restrict__ Wo,
    _Float16* __restrict__ xh, _Float16* __restrict__ W3h,
    _Float16* __restrict__ Woh)
{
    const int bid = blockIdx.x;
    const float* s; _Float16* d; int blk;
    if (bid < 2048) { s = x; d = xh; blk = bid; }
    else {
        const int idx = bid - 2048;
        const int w   = idx >> 9;          // 0..3
        blk = idx & 511;
        s = (w == 0) ? Wq : (w == 1) ? Wk : (w == 2) ? Wv : Wo;
        d = (w == 3) ? Woh : W3h + (size_t)w * (DD * DD);
    }
    const int i = (blk * 256 + threadIdx.x) * 8;
    float4 a = *(const float4*)(s + i);
    float4 b = *(const float4*)(s + i + 4);
    union { _Float16 h[8]; int4 v; } u;
    u.h[0] = (_Float16)a.x; u.h[1] = (_Float16)a.y;
    u.h[2] = (_Float16)a.z; u.h[3] = (_Float16)a.w;
    u.h[4] = (_Float16)b.x; u.h[5] = (_Float16)b.y;
    u.h[6] = (_Float16)b.z; u.h[7] = (_Float16)b.w;
    *(int4*)(d + i) = u.v;
}

// ---------------------------------------------------------------------------
// m97-class f16 MFMA GEMM: 128x128 tile, BK=64, 4 waves (2x2, 64x64 each).
// Chunk-major LDS [kc][row][8]; g2lds16 lane->slot contiguous.
// NPROD=2 adds the Al low-half product (Wo GEMM).
// EPI=0: C = acc + bias (fp32, the final output).
// EPI=1: fused QKV epilogue. A 128-wide tile covers exactly 2 complete
//   64-wide head segments, and each wave's 64x64 sub-tile holds full rows
//   of one segment -> l2norm in-register: ss = sum over 4 tn-frags of
//   acc^2, 4-step shfl_xor over the 16-lane group, inv = rsqrt(max(ss,
//   1e-24)) == 1/max(sqrt(ss),1e-12). seg(n0g>>10): 0 -> Qh, 1 -> Kh
//   (normalized f16, [b][h][t][dk]), 2 -> Vh (f16 passthrough, [row][d]).
//   Numerically identical to the old fp32-C + norm_kernel path.
// 1D grid + XCD swizzle (nwg % 8 == 0).
// ---------------------------------------------------------------------------
template<int NPROD, int EPI>
__global__ __launch_bounds__(256, NPROD == 1 ? 3 : 2) void gemm_f16_128(
    const _Float16* __restrict__ Ah_g, const _Float16* __restrict__ Al_g,
    const _Float16* __restrict__ B_g, const float* __restrict__ bias,
    float* __restrict__ C,
    _Float16* __restrict__ Qh, _Float16* __restrict__ Kh,
    _Float16* __restrict__ Vh,
    int nbx, int K, int hasBias)
{
    __shared__ _Float16 Ahs[8][128][8];                    // 16 KB
    __shared__ _Float16 Bhs[8][128][8];                    // 16 KB
    __shared__ _Float16 Als[NPROD == 2 ? 8 : 1][128][8];   // 16 KB / 2 KB

    // XCD-bijective swizzle (nwg multiple of 8)
    const int nwg  = gridDim.x;
    const int wgid = blockIdx.x;
    const int cpx  = nwg >> 3;
    const int swz  = (wgid & 7) * cpx + (wgid >> 3);
    const int by   = swz / nbx;
    const int bx   = swz - by * nbx;

    const int t    = threadIdx.x;
    const int m0   = by * 128;
    const int n0g  = bx * 128;
    const int seg  = n0g >> 10;
    const int n0   = n0g & 1023;

    const int lane = t & 63;
    const int w    = t >> 6;
    const int wm   = w >> 1;
    const int wn   = w & 1;
    const int l15  = lane & 15;
    const int quad = lane >> 4;

    f32x4 acc[4][4];
#pragma unroll
    for (int i = 0; i < 4; ++i)
#pragma unroll
        for (int j = 0; j < 4; ++j) acc[i][j] = (f32x4)0.f;

    for (int k0 = 0; k0 < K; k0 += 64) {
        __syncthreads();   // previous chunk's frag reads done
        // staging: wave w handles chunks cc = 2w, 2w+1 (128 rows = 2 halves)
#pragma unroll
        for (int i = 0; i < 2; ++i) {
            const int cc = w * 2 + i;
#pragma unroll
            for (int half = 0; half < 2; ++half) {
                g2lds16(Ah_g + (size_t)(m0 + half * 64 + lane) * K + k0 + cc * 8,
                        &Ahs[cc][half * 64][0]);
                if (NPROD == 2)
                    g2lds16(Al_g + (size_t)(m0 + half * 64 + lane) * K + k0 + cc * 8,
                            &Als[cc][half * 64][0]);
                g2lds16(B_g + (size_t)(n0g + half * 64 + lane) * K + k0 + cc * 8,
                        &Bhs[cc][half * 64][0]);
            }
        }
        __syncthreads();   // vmcnt drained

#pragma unroll
        for (int kh = 0; kh < 2; ++kh) {
            f16x8 ah[4], bh[4];
#pragma unroll
            for (int tm = 0; tm < 4; ++tm)
                ah[tm] = *(const f16x8*)&Ahs[kh * 4 + quad][wm * 64 + tm * 16 + l15][0];
#pragma unroll
            for (int tn = 0; tn < 4; ++tn)
                bh[tn] = *(const f16x8*)&Bhs[kh * 4 + quad][wn * 64 + tn * 16 + l15][0];
#pragma unroll
            for (int tm = 0; tm < 4; ++tm)
#pragma unroll
                for (int tn = 0; tn < 4; ++tn)
                    acc[tm][tn] = __builtin_amdgcn_mfma_f32_16x16x32_f16(
                        ah[tm], bh[tn], acc[tm][tn], 0, 0, 0);
            if (NPROD == 2) {
                f16x8 al[4];
#pragma unroll
                for (int tm = 0; tm < 4; ++tm)
                    al[tm] = *(const f16x8*)&Als[kh * 4 + quad][wm * 64 + tm * 16 + l15][0];
#pragma unroll
                for (int tm = 0; tm < 4; ++tm)
#pragma unroll
                    for (int tn = 0; tn < 4; ++tn)
                        acc[tm][tn] = __builtin_amdgcn_mfma_f32_16x16x32_f16(
                            al[tm], bh[tn], acc[tm][tn], 0, 0, 0);
            }
        }
    }

    if (EPI == 0) {
#pragma unroll
        for (int tm = 0; tm < 4; ++tm)
#pragma unroll
            for (int tn = 0; tn < 4; ++tn) {
                const int col  = n0 + wn * 64 + tn * 16 + l15;
                const float bv = hasBias ? bias[col] : 0.f;
                const int rowb = m0 + wm * 64 + tm * 16 + quad * 4;
#pragma unroll
                for (int r = 0; r < 4; ++r)
                    C[(size_t)(rowb + r) * 1024 + col] = acc[tm][tn][r] + bv;
            }
    } else {
        if (seg < 2) {
            // normalize each row's 64-wide head segment, emit f16 [b][h][t][dk]
            _Float16* __restrict__ dstb = (seg == 0) ? Qh : Kh;
            const int hh = (n0 >> 6) + wn;   // head index
#pragma unroll
            for (int tm = 0; tm < 4; ++tm) {
#pragma unroll
                for (int r = 0; r < 4; ++r) {
                    float ss = 0.f;
#pragma unroll
                    for (int tn = 0; tn < 4; ++tn) {
                        const float v = acc[tm][tn][r];
                        ss += v * v;
                    }
                    ss += __shfl_xor(ss, 1);
                    ss += __shfl_xor(ss, 2);
                    ss += __shfl_xor(ss, 4);
                    ss += __shfl_xor(ss, 8);
                    const float inv = rsqrtf(fmaxf(ss, 1e-24f));
                    const int row = m0 + wm * 64 + tm * 16 + quad * 4 + r;
                    const int b   = row >> 11;
                    const int tt  = row & 2047;
                    _Float16* dst = dstb + ((size_t)(b * HH + hh) * TT + tt) * DK;
#pragma unroll
                    for (int tn = 0; tn < 4; ++tn)
                        dst[tn * 16 + l15] = (_Float16)(acc[tm][tn][r] * inv);
                }
            }
        } else {
            // V passthrough: f16 [row][1024]
#pragma unroll
            for (int tm = 0; tm < 4; ++tm)
#pragma unroll
                for (int tn = 0; tn < 4; ++tn) {
                    const int col  = n0 + wn * 64 + tn * 16 + l15;
                    const int rowb = m0 + wm * 64 + tm * 16 + quad * 4;
#pragma unroll
                    for (int r = 0; r < 4; ++r)
                        Vh[(size_t)(rowb + r) * 1024 + col] =
                            (_Float16)acc[tm][tn][r];
                }
        }
    }
}

// ---------------------------------------------------------------------------
// V (f16 [b*T][1024]) -> f16 transposed [b][h][d][T].
// ---------------------------------------------------------------------------
__global__ __launch_bounds__(256) void vtrans_kernel(
    const _Float16* __restrict__ Vh, _Float16* __restrict__ Vt)
{
    __shared__ _Float16 Vtmp[64][72];
    const int t  = threadIdx.x;
    const int t0 = blockIdx.x * 64;
    const int h  = blockIdx.y;
    const int b  = blockIdx.z;

    {
        const int i  = t >> 2;            // token row 0..63
        const int jc = (t & 3) * 16;      // dim chunk
        const _Float16* src = Vh + (size_t)(b * TT + t0 + i) * DD + h * DK + jc;
        f16x8 a = *(const f16x8*)(src);
        f16x8 c = *(const f16x8*)(src + 8);
#pragma unroll
        for (int e = 0; e < 8; ++e) {
            Vtmp[jc + e][i]     = a[e];
            Vtmp[jc + 8 + e][i] = c[e];
        }
    }
    __syncthreads();
    {
        const int d  = t >> 2;
        const int kc = (t & 3) * 16;
        _Float16* dst = Vt + ((size_t)((b * HH + h) * DK + d)) * TT + t0 + kc;
        *(int4*)(dst)     = *(const int4*)&Vtmp[d][kc];
        *(int4*)(dst + 8) = *(const int4*)&Vtmp[d][kc + 8];
    }
}

// ---------------------------------------------------------------------------
// MFMA angular attention v8 — all-f16. Grid (T/64, H, B), 256 threads.
//  - V staged in LDS (shared by 4 waves), double-buffered, issued a full
//    tile ahead so the barrier's vmcnt(0) drain hits arrived loads.
//  - K fragments from global into registers, prefetched one tile ahead.
//  - Q fragments in registers.
//  - Ws single-buffered, 2 barriers/tile; neither drains a fresh load.
// LDS 51456 B -> 3 blocks/CU.
// ---------------------------------------------------------------------------
__global__ __launch_bounds__(256, 3) void attn_kernel(
    const _Float16* __restrict__ Qh_g, const _Float16* __restrict__ Kh_g,
    const _Float16* __restrict__ Vt_g,
    _Float16* __restrict__ Oh, _Float16* __restrict__ Ol)
{
    __shared__ _Float16 Vts[2][16][64][8]; // [buf][key-chunk][d][8] 32768 B
    __shared__ _Float16 Ws[64][136];       // [q][key]               17408 B
    __shared__ float Rbuf[4][64];          //                         1024 B
    __shared__ float Rfin[64];             //                          256 B

    const int t    = threadIdx.x;
    const int lane = t & 63;
    const int w    = t >> 6;
    const int l15  = lane & 15;
    const int quad = lane >> 4;
    const int q0   = blockIdx.x * 64;
    const int h    = blockIdx.y;
    const int b    = blockIdx.z;
    const size_t bh = (size_t)(b * HH + h);

    const _Float16* kh_g = Kh_g + bh * TT * DK;
    const _Float16* vt_g = Vt_g + bh * (size_t)DK * TT;

    // Q fragments in registers (loaded once, L2-served)
    f16x8 qf[4][2];
#pragma unroll
    for (int qt = 0; qt < 4; ++qt)
#pragma unroll
        for (int s = 0; s < 2; ++s)
            qf[qt][s] = *(const f16x8*)(Qh_g + (bh * TT + q0 + qt * 16 + l15) * DK
                                        + s * 32 + quad * 8);

    // K fragments for tile 0 (wave's 32 keys; 16B contiguous per lane)
    f16x8 kf[2][2], kfn[2][2];
#pragma unroll
    for (int s = 0; s < 2; ++s)
#pragma unroll
        for (int mt = 0; mt < 2; ++mt)
            kf[s][mt] = *(const f16x8*)(kh_g
                + (size_t)(w * 32 + mt * 16 + l15) * DK + s * 32 + quad * 8);

    // stage V tile 0 into buffer 0
#pragma unroll
    for (int j = 0; j < 4; ++j) {
        const int kc = w * 4 + j;
        g2lds16(vt_g + (size_t)lane * TT + kc * 8, &Vts[0][kc][0][0]);
    }

    f32x4 acc[4];    // O[16q x 64d] for q-tile w
#pragma unroll
    for (int j = 0; j < 4; ++j) acc[j] = (f32x4)0.f;
    f32x2 rs2[4];
#pragma unroll
    for (int j = 0; j < 4; ++j) rs2[j] = (f32x2)0.f;

    int vb = 0;
    for (int k0 = 0; k0 < TT; k0 += KT, vb ^= 1) {
        const int kn = k0 + KT;
        if (kn < TT) {
            // stage V[t+1] into the other buffer (consumed after NEXT BAR1)
#pragma unroll
            for (int j = 0; j < 4; ++j) {
                const int kc = w * 4 + j;
                g2lds16(vt_g + (size_t)lane * TT + kn + kc * 8,
                        &Vts[vb ^ 1][kc][0][0]);
            }
            // prefetch K fragments for tile t+1
#pragma unroll
            for (int s = 0; s < 2; ++s)
#pragma unroll
                for (int mt = 0; mt < 2; ++mt)
                    kfn[s][mt] = *(const f16x8*)(kh_g
                        + (size_t)(kn + w * 32 + mt * 16 + l15) * DK
                        + s * 32 + quad * 8);
        }

        // Phase A: S^T for wave's 32 keys x 64 q, transform, write Ws
#pragma unroll
        for (int qt = 0; qt < 4; ++qt) {
            f32x4 c_[2];
            c_[0] = (f32x4)0.f;
            c_[1] = (f32x4)0.f;
#pragma unroll
            for (int s = 0; s < 2; ++s) {
#pragma unroll
                for (int mt = 0; mt < 2; ++mt)
                    c_[mt] = __builtin_amdgcn_mfma_f32_16x16x32_f16(
                        kf[s][mt], qf[qt][s], c_[mt], 0, 0, 0);
            }
#pragma unroll
            for (int mt = 0; mt < 2; ++mt) {
                f32x2 p01, p23;
                p01.x = c_[mt][0]; p01.y = c_[mt][1];
                p23.x = c_[mt][2]; p23.y = c_[mt][3];
                f32x2 w01 = w8pair(p01, rs2[qt]);
                f32x2 w23 = w8pair(p23, rs2[qt]);
                int2 pk;
                pk.x = packh2(w01);
                pk.y = packh2(w23);
                *(int2*)&Ws[qt * 16 + l15][w * 32 + mt * 16 + quad * 4] = pk;
            }
        }
        __syncthreads();   // BAR1: Ws ready; V[t] (staged last iter) arrived

        // Phase B: PV for q-tile w over all 128 keys from Vts[vb]
#pragma unroll
        for (int kstep = 0; kstep < 4; ++kstep) {
            f16x8 av = *(const f16x8*)&Ws[16 * w + l15][kstep * 32 + quad * 8];
#pragma unroll
            for (int nd = 0; nd < 4; ++nd) {
                f16x8 bv = *(const f16x8*)&Vts[vb][kstep * 4 + quad][nd * 16 + l15][0];
                acc[nd] = __builtin_amdgcn_mfma_f32_16x16x32_f16(
                    av, bv, acc[nd], 0, 0, 0);
            }
        }
        __syncthreads();   // BAR2: Ws reads done; Vts[vb^1] reads of t-1 done

        // roll K prefetch
#pragma unroll
        for (int s = 0; s < 2; ++s)
#pragma unroll
            for (int mt = 0; mt < 2; ++mt)
                kf[s][mt] = kfn[s][mt];
    }

    // rowsum: rs2[qt] covers q = qt*16+l15 over wave's keys
#pragma unroll
    for (int qt = 0; qt < 4; ++qt) {
        float pr = rs2[qt].x + rs2[qt].y;
        pr += __shfl_xor(pr, 16);
        pr += __shfl_xor(pr, 32);
        if (quad == 0) Rbuf[w][qt * 16 + l15] = pr;
    }
    __syncthreads();
    if (t < 64) {
        float s = Rbuf[0][t] + Rbuf[1][t] + Rbuf[2][t] + Rbuf[3][t];
        Rfin[t] = 1.f / (s + 1e-6f);
    }
    __syncthreads();

    // store: O split hi/lo f16 (feeds the 2-product Wo GEMM)
#pragma unroll
    for (int r = 0; r < 4; ++r) {
        const int q = 16 * w + quad * 4 + r;
        const float inv = Rfin[q];
        const size_t base = (size_t)(b * TT + q0 + q) * DD + h * DK + l15;
#pragma unroll
        for (int nd = 0; nd < 4; ++nd) {
            float v = acc[nd][r] * inv;
            _Float16 hv = (_Float16)v;
            Oh[base + nd * 16] = hv;
            Ol[base + nd * 16] = (_Float16)(v - (float)hv);
        }
    }
}

// ---------------------------------------------------------------------------
extern "C" void kernel_launch(void* const* d_in, const int* in_sizes, int n_in,
                              void* d_out, int out_size, void* d_ws, size_t ws_size,
                              hipStream_t stream)
{
    const float* x  = (const float*)d_in[0];
    const float* Wq = (const float*)d_in[1];
    const float* Wk = (const float*)d_in[2];
    const float* Wv = (const float*)d_in[3];
    const float* Wo = (const float*)d_in[4];
    const float* bo = (const float*)d_in[5];
    float* out = (float*)d_out;

    const int M = BB * TT;   // 4096
    const int K = DD;

    const size_t MB = 1024 * 1024;
    char* ws = (char*)d_ws;
    // [0,8):   xh f16      -> Oh f16 (after QKV GEMM consumed xh)
    // [8,14):  W3h f16 = [Wq;Wk;Wv] rows (3072x1024, 6 MB)
    // [14,16): Woh f16 (persists)
    // [16,24): Qh f16 (normalized, [b][h][t][dk])
    // [24,32): Kh f16 (normalized)
    // [32,40): Vh f16 [row][1024] -> Ol f16 (after vtrans consumed Vh)
    // [40,48): Vt f16 [b][h][d][T]
    _Float16* xh  = (_Float16*)(ws);
    _Float16* W3h = (_Float16*)(ws + 8 * MB);
    _Float16* Woh = (_Float16*)(ws + 14 * MB);
    _Float16* Qh  = (_Float16*)(ws + 16 * MB);
    _Float16* Kh  = (_Float16*)(ws + 24 * MB);
    _Float16* Vh  = (_Float16*)(ws + 32 * MB);
    _Float16* Vt  = (_Float16*)(ws + 40 * MB);
    _Float16* Oh  = (_Float16*)(ws);            // xh dead after QKV GEMM
    _Float16* Ol  = (_Float16*)(ws + 32 * MB);  // Vh dead after vtrans

    dim3 gB(256);

    // 1) convert x + all weights to f16 (one launch)
    cvtall_kernel<<<4096, gB, 0, stream>>>(x, Wq, Wk, Wv, Wo, xh, W3h, Woh);

    // 2) fused QKV projection + l2norm epilogue -> Qh/Kh (normalized f16)
    //    and Vh (f16 passthrough). One 128x128-tile GEMM, B = [Wq;Wk;Wv].
    {
        const int nbx = 3072 / 128;              // 24
        const int nby = M / 128;                 // 32
        gemm_f16_128<1, 1><<<nbx * nby, gB, 0, stream>>>(
            xh, nullptr, W3h, nullptr, nullptr, Qh, Kh, Vh, nbx, K, 0);
    }

    // 3) V transpose (f16 in, f16 out)
    vtrans_kernel<<<dim3(TT / 64, HH, BB), gB, 0, stream>>>(Vh, Vt);

    // 4) fused angular attention -> O split f16 hi/lo
    attn_kernel<<<dim3(TT / 64, HH, BB), gB, 0, stream>>>(Qh, Kh, Vt, Oh, Ol);

    // 5) output projection: (Oh + Ol) @ Woh^T + bo
    {
        const int nbx = 1024 / 128;              // 8
        const int nby = M / 128;                 // 32
        gemm_f16_128<2, 0><<<nbx * nby, gB, 0, stream>>>(
            Oh, Ol, Woh, bo, out, nullptr, nullptr, nullptr, nbx, K, 1);
    }
}

// Round 6
// 310.759 us; speedup vs baseline: 1.3158x; 1.0490x over previous
//
#include <hip/hip_runtime.h>
#include <hip/hip_bf16.h>
#include <hip/hip_fp16.h>
#include <math.h>

// Problem constants
#define BB 2
#define TT 2048
#define DD 1024
#define HH 16
#define DK 64
#define KT 64             // keys per attention tile (v9: 64)

typedef _Float16 f16x8 __attribute__((ext_vector_type(8)));
typedef __fp16 fp16x2 __attribute__((ext_vector_type(2)));
typedef __attribute__((ext_vector_type(4))) float f32x4;
typedef __attribute__((ext_vector_type(2))) float f32x2;

// async 16B global->LDS (lane i writes ldsbase + i*16)
static __device__ __forceinline__ void g2lds16(const void* g, void* l) {
    __builtin_amdgcn_global_load_lds(
        (const __attribute__((address_space(1))) unsigned int*)g,
        (__attribute__((address_space(3))) unsigned int*)l, 16, 0, 0);
}

// w = (1 - acos(clip(s,±0.999))/pi)^8 for a pair; rs accumulates pair sums.
// acos/pi via A&S 4.4.45 deg-3 (|err|<=5e-5 rad); reference's max(.,1e-6)
// is dead (clamp => t >= 0.0142). float2 ops lower to v_pk_* on gfx950.
static __device__ __forceinline__ f32x2 w8pair(f32x2 s, f32x2& rs) {
    f32x2 ax;
    ax.x = fminf(fabsf(s.x), 0.999f);
    ax.y = fminf(fabsf(s.y), 0.999f);
    f32x2 p = ax * -0.0059617f + 0.0236380f;
    p = p * ax + (-0.0675180f);
    p = p * ax + 0.49997851f;
    f32x2 om = 1.0f - ax;
    f32x2 u;
    u.x = sqrtf(om.x);
    u.y = sqrtf(om.y);
    f32x2 uq = u * p;
    f32x2 e = 0.5f - uq;
    f32x2 t;
    t.x = 0.5f + copysignf(e.x, s.x);
    t.y = 0.5f + copysignf(e.y, s.y);
    f32x2 t2 = t * t;
    f32x2 t4 = t2 * t2;
    f32x2 t8 = t4 * t4;
    rs += t8;
    return t8;
}
// one-instruction f16 pair pack (RTZ; |err|<=2^-11 rel, fine for W)
static __device__ __forceinline__ int packh2(f32x2 v) {
    union { fp16x2 h; int i; } u;
    u.h = __builtin_amdgcn_cvt_pkrtz(v.x, v.y);
    return u.i;
}

// ---------------------------------------------------------------------------
// One-launch fp32 -> f16 convert for x + all 4 weight matrices.
// bid < 2048: x -> xh. Else weights: Wq/Wk/Wv -> W3h rows (contiguous),
// Wo -> Woh. 8 elems/thread.
// ---------------------------------------------------------------------------
__global__ __launch_bounds__(256) void cvtall_kernel(
    const float* __restrict__ x,  const float* __restrict__ Wq,
    const float* __restrict__ Wk, const float* __restrict__ Wv,
    const float* __restrict__ Wo,
    _Float16* __restrict__ xh, _Float16* __restrict__ W3h,
    _Float16* __restrict__ Woh)
{
    const int bid = blockIdx.x;
    const float* s; _Float16* d; int blk;
    if (bid < 2048) { s = x; d = xh; blk = bid; }
    else {
        const int idx = bid - 2048;
        const int w   = idx >> 9;          // 0..3
        blk = idx & 511;
        s = (w == 0) ? Wq : (w == 1) ? Wk : (w == 2) ? Wv : Wo;
        d = (w == 3) ? Woh : W3h + (size_t)w * (DD * DD);
    }
    const int i = (blk * 256 + threadIdx.x) * 8;
    float4 a = *(const float4*)(s + i);
    float4 b = *(const float4*)(s + i + 4);
    union { _Float16 h[8]; int4 v; } u;
    u.h[0] = (_Float16)a.x; u.h[1] = (_Float16)a.y;
    u.h[2] = (_Float16)a.z; u.h[3] = (_Float16)a.w;
    u.h[4] = (_Float16)b.x; u.h[5] = (_Float16)b.y;
    u.h[6] = (_Float16)b.z; u.h[7] = (_Float16)b.w;
    *(int4*)(d + i) = u.v;
}

// ---------------------------------------------------------------------------
// m97-class f16 MFMA GEMM: 128x128 tile, BK=64, 4 waves (2x2, 64x64 each).
// Chunk-major LDS [kc][row][8]; g2lds16 lane->slot contiguous.
// NPROD=2 adds the Al low-half product (Wo GEMM).
// EPI=0: C = acc + bias (fp32, the final output).
// EPI=1: fused QKV epilogue. A 128-wide tile covers exactly 2 complete
//   64-wide head segments; each wave's 64x64 sub-tile holds full rows of
//   one segment -> l2norm in-register (shfl_xor over 16-lane group,
//   rsqrt). seg(n0g>>10): 0 -> Qh, 1 -> Kh (normalized f16,
//   [b][h][t][dk]), 2 -> Vh (f16 passthrough, [row][d]).
// 1D grid + XCD swizzle (nwg % 8 == 0).
// ---------------------------------------------------------------------------
template<int NPROD, int EPI>
__global__ __launch_bounds__(256, NPROD == 1 ? 3 : 2) void gemm_f16_128(
    const _Float16* __restrict__ Ah_g, const _Float16* __restrict__ Al_g,
    const _Float16* __restrict__ B_g, const float* __restrict__ bias,
    float* __restrict__ C,
    _Float16* __restrict__ Qh, _Float16* __restrict__ Kh,
    _Float16* __restrict__ Vh,
    int nbx, int K, int hasBias)
{
    __shared__ _Float16 Ahs[8][128][8];                    // 16 KB
    __shared__ _Float16 Bhs[8][128][8];                    // 16 KB
    __shared__ _Float16 Als[NPROD == 2 ? 8 : 1][128][8];   // 16 KB / 2 KB

    // XCD-bijective swizzle (nwg multiple of 8)
    const int nwg  = gridDim.x;
    const int wgid = blockIdx.x;
    const int cpx  = nwg >> 3;
    const int swz  = (wgid & 7) * cpx + (wgid >> 3);
    const int by   = swz / nbx;
    const int bx   = swz - by * nbx;

    const int t    = threadIdx.x;
    const int m0   = by * 128;
    const int n0g  = bx * 128;
    const int seg  = n0g >> 10;
    const int n0   = n0g & 1023;

    const int lane = t & 63;
    const int w    = t >> 6;
    const int wm   = w >> 1;
    const int wn   = w & 1;
    const int l15  = lane & 15;
    const int quad = lane >> 4;

    f32x4 acc[4][4];
#pragma unroll
    for (int i = 0; i < 4; ++i)
#pragma unroll
        for (int j = 0; j < 4; ++j) acc[i][j] = (f32x4)0.f;

    for (int k0 = 0; k0 < K; k0 += 64) {
        __syncthreads();   // previous chunk's frag reads done
        // staging: wave w handles chunks cc = 2w, 2w+1 (128 rows = 2 halves)
#pragma unroll
        for (int i = 0; i < 2; ++i) {
            const int cc = w * 2 + i;
#pragma unroll
            for (int half = 0; half < 2; ++half) {
                g2lds16(Ah_g + (size_t)(m0 + half * 64 + lane) * K + k0 + cc * 8,
                        &Ahs[cc][half * 64][0]);
                if (NPROD == 2)
                    g2lds16(Al_g + (size_t)(m0 + half * 64 + lane) * K + k0 + cc * 8,
                            &Als[cc][half * 64][0]);
                g2lds16(B_g + (size_t)(n0g + half * 64 + lane) * K + k0 + cc * 8,
                        &Bhs[cc][half * 64][0]);
            }
        }
        __syncthreads();   // vmcnt drained

#pragma unroll
        for (int kh = 0; kh < 2; ++kh) {
            f16x8 ah[4], bh[4];
#pragma unroll
            for (int tm = 0; tm < 4; ++tm)
                ah[tm] = *(const f16x8*)&Ahs[kh * 4 + quad][wm * 64 + tm * 16 + l15][0];
#pragma unroll
            for (int tn = 0; tn < 4; ++tn)
                bh[tn] = *(const f16x8*)&Bhs[kh * 4 + quad][wn * 64 + tn * 16 + l15][0];
#pragma unroll
            for (int tm = 0; tm < 4; ++tm)
#pragma unroll
                for (int tn = 0; tn < 4; ++tn)
                    acc[tm][tn] = __builtin_amdgcn_mfma_f32_16x16x32_f16(
                        ah[tm], bh[tn], acc[tm][tn], 0, 0, 0);
            if (NPROD == 2) {
                f16x8 al[4];
#pragma unroll
                for (int tm = 0; tm < 4; ++tm)
                    al[tm] = *(const f16x8*)&Als[kh * 4 + quad][wm * 64 + tm * 16 + l15][0];
#pragma unroll
                for (int tm = 0; tm < 4; ++tm)
#pragma unroll
                    for (int tn = 0; tn < 4; ++tn)
                        acc[tm][tn] = __builtin_amdgcn_mfma_f32_16x16x32_f16(
                            al[tm], bh[tn], acc[tm][tn], 0, 0, 0);
            }
        }
    }

    if (EPI == 0) {
#pragma unroll
        for (int tm = 0; tm < 4; ++tm)
#pragma unroll
            for (int tn = 0; tn < 4; ++tn) {
                const int col  = n0 + wn * 64 + tn * 16 + l15;
                const float bv = hasBias ? bias[col] : 0.f;
                const int rowb = m0 + wm * 64 + tm * 16 + quad * 4;
#pragma unroll
                for (int r = 0; r < 4; ++r)
                    C[(size_t)(rowb + r) * 1024 + col] = acc[tm][tn][r] + bv;
            }
    } else {
        if (seg < 2) {
            // normalize each row's 64-wide head segment, emit f16 [b][h][t][dk]
            _Float16* __restrict__ dstb = (seg == 0) ? Qh : Kh;
            const int hh = (n0 >> 6) + wn;   // head index
#pragma unroll
            for (int tm = 0; tm < 4; ++tm) {
#pragma unroll
                for (int r = 0; r < 4; ++r) {
                    float ss = 0.f;
#pragma unroll
                    for (int tn = 0; tn < 4; ++tn) {
                        const float v = acc[tm][tn][r];
                        ss += v * v;
                    }
                    ss += __shfl_xor(ss, 1);
                    ss += __shfl_xor(ss, 2);
                    ss += __shfl_xor(ss, 4);
                    ss += __shfl_xor(ss, 8);
                    const float inv = rsqrtf(fmaxf(ss, 1e-24f));
                    const int row = m0 + wm * 64 + tm * 16 + quad * 4 + r;
                    const int b   = row >> 11;
                    const int tt  = row & 2047;
                    _Float16* dst = dstb + ((size_t)(b * HH + hh) * TT + tt) * DK;
#pragma unroll
                    for (int tn = 0; tn < 4; ++tn)
                        dst[tn * 16 + l15] = (_Float16)(acc[tm][tn][r] * inv);
                }
            }
        } else {
            // V passthrough: f16 [row][1024]
#pragma unroll
            for (int tm = 0; tm < 4; ++tm)
#pragma unroll
                for (int tn = 0; tn < 4; ++tn) {
                    const int col  = n0 + wn * 64 + tn * 16 + l15;
                    const int rowb = m0 + wm * 64 + tm * 16 + quad * 4;
#pragma unroll
                    for (int r = 0; r < 4; ++r)
                        Vh[(size_t)(rowb + r) * 1024 + col] =
                            (_Float16)acc[tm][tn][r];
                }
        }
    }
}

// ---------------------------------------------------------------------------
// V (f16 [b*T][1024]) -> f16 transposed [b][h][d][T].
// ---------------------------------------------------------------------------
__global__ __launch_bounds__(256) void vtrans_kernel(
    const _Float16* __restrict__ Vh, _Float16* __restrict__ Vt)
{
    __shared__ _Float16 Vtmp[64][72];
    const int t  = threadIdx.x;
    const int t0 = blockIdx.x * 64;
    const int h  = blockIdx.y;
    const int b  = blockIdx.z;

    {
        const int i  = t >> 2;            // token row 0..63
        const int jc = (t & 3) * 16;      // dim chunk
        const _Float16* src = Vh + (size_t)(b * TT + t0 + i) * DD + h * DK + jc;
        f16x8 a = *(const f16x8*)(src);
        f16x8 c = *(const f16x8*)(src + 8);
#pragma unroll
        for (int e = 0; e < 8; ++e) {
            Vtmp[jc + e][i]     = a[e];
            Vtmp[jc + 8 + e][i] = c[e];
        }
    }
    __syncthreads();
    {
        const int d  = t >> 2;
        const int kc = (t & 3) * 16;
        _Float16* dst = Vt + ((size_t)((b * HH + h) * DK + d)) * TT + t0 + kc;
        *(int4*)(dst)     = *(const int4*)&Vtmp[d][kc];
        *(int4*)(dst + 8) = *(const int4*)&Vtmp[d][kc + 8];
    }
}

// ---------------------------------------------------------------------------
// MFMA angular attention v9 — all-f16. Grid (T/64, H, B), 256 threads.
// KT=64 retile for full residency: LDS 36.1 KB -> 4 blocks/CU; grid 1024 =
// exactly 4/CU, ALL blocks resident from t=0 (no tail round).
// ONE barrier per tile: Ws double-buffered (A(t) writes Ws[p], B(t) reads
// Ws[p] after BAR; A(t+1) writes Ws[p^1] which B(t-1) finished before
// BAR(t)). V staged after BAR into Vts[p^1] (last reader B(t-1) drained at
// BAR(t)); consumed at B(t+1) after BAR(t+1) drains the issuer's vmcnt.
// K fragments prefetched into registers one tile ahead.
// ---------------------------------------------------------------------------
__global__ __launch_bounds__(256, 4) void attn_kernel(
    const _Float16* __restrict__ Qh_g, const _Float16* __restrict__ Kh_g,
    const _Float16* __restrict__ Vt_g,
    _Float16* __restrict__ Oh, _Float16* __restrict__ Ol)
{
    __shared__ _Float16 Vts[2][8][64][8];  // [buf][key-chunk][d][8] 16384 B
    __shared__ _Float16 Ws[2][64][72];     // [buf][q][key]          18432 B
    __shared__ float Rbuf[4][64];          //                         1024 B
    __shared__ float Rfin[64];             //                          256 B

    const int t    = threadIdx.x;
    const int lane = t & 63;
    const int w    = t >> 6;
    const int l15  = lane & 15;
    const int quad = lane >> 4;
    const int q0   = blockIdx.x * 64;
    const int h    = blockIdx.y;
    const int b    = blockIdx.z;
    const size_t bh = (size_t)(b * HH + h);

    const _Float16* kh_g = Kh_g + bh * TT * DK;
    const _Float16* vt_g = Vt_g + bh * (size_t)DK * TT;

    // Q fragments in registers (loaded once, L2-served)
    f16x8 qf[4][2];
#pragma unroll
    for (int qt = 0; qt < 4; ++qt)
#pragma unroll
        for (int s = 0; s < 2; ++s)
            qf[qt][s] = *(const f16x8*)(Qh_g + (bh * TT + q0 + qt * 16 + l15) * DK
                                        + s * 32 + quad * 8);

    // K fragments for tile 0 (wave's 16 keys; 16B contiguous per lane)
    f16x8 kf[2], kfn[2];
#pragma unroll
    for (int s = 0; s < 2; ++s) {
        kf[s] = *(const f16x8*)(kh_g
            + (size_t)(w * 16 + l15) * DK + s * 32 + quad * 8);
        kfn[s] = kf[s];
    }

    // stage V tile 0 into buffer 0 (8 KB; wave w covers chunks 2w, 2w+1)
#pragma unroll
    for (int j = 0; j < 2; ++j) {
        const int kc = w * 2 + j;
        g2lds16(vt_g + (size_t)lane * TT + kc * 8, &Vts[0][kc][0][0]);
    }

    f32x4 acc[4];    // O[16q x 64d] for q-tile w
#pragma unroll
    for (int j = 0; j < 4; ++j) acc[j] = (f32x4)0.f;
    f32x2 rs2[4];
#pragma unroll
    for (int j = 0; j < 4; ++j) rs2[j] = (f32x2)0.f;

    int p = 0;
    for (int k0 = 0; k0 < TT; k0 += KT, p ^= 1) {
        const int kn = k0 + KT;
        if (kn < TT) {
            // prefetch K fragments for tile t+1 (consumed after kf roll)
#pragma unroll
            for (int s = 0; s < 2; ++s)
                kfn[s] = *(const f16x8*)(kh_g
                    + (size_t)(kn + w * 16 + l15) * DK + s * 32 + quad * 8);
        }

        // Phase A: S^T for wave's 16 keys x 64 q, transform, write Ws[p]
#pragma unroll
        for (int qt = 0; qt < 4; ++qt) {
            f32x4 c_ = (f32x4)0.f;
#pragma unroll
            for (int s = 0; s < 2; ++s)
                c_ = __builtin_amdgcn_mfma_f32_16x16x32_f16(
                    kf[s], qf[qt][s], c_, 0, 0, 0);
            f32x2 p01, p23;
            p01.x = c_[0]; p01.y = c_[1];
            p23.x = c_[2]; p23.y = c_[3];
            f32x2 w01 = w8pair(p01, rs2[qt]);
            f32x2 w23 = w8pair(p23, rs2[qt]);
            int2 pk;
            pk.x = packh2(w01);
            pk.y = packh2(w23);
            *(int2*)&Ws[p][qt * 16 + l15][w * 16 + quad * 4] = pk;
        }
        __syncthreads();   // BAR(t): Ws[p] ready; V[t] arrived (staged t-1);
                           // B(t-1)'s Ws[p^1]/Vts[p^1] reads drained

        if (kn < TT) {
            // stage V[t+1] into the other buffer (consumed after BAR(t+1))
#pragma unroll
            for (int j = 0; j < 2; ++j) {
                const int kc = w * 2 + j;
                g2lds16(vt_g + (size_t)lane * TT + kn + kc * 8,
                        &Vts[p ^ 1][kc][0][0]);
            }
        }

        // Phase B: PV for q-tile w over the tile's 64 keys from Vts[p]
#pragma unroll
        for (int kstep = 0; kstep < 2; ++kstep) {
            f16x8 av = *(const f16x8*)&Ws[p][16 * w + l15][kstep * 32 + quad * 8];
#pragma unroll
            for (int nd = 0; nd < 4; ++nd) {
                f16x8 bv = *(const f16x8*)&Vts[p][kstep * 4 + quad][nd * 16 + l15][0];
                acc[nd] = __builtin_amdgcn_mfma_f32_16x16x32_f16(
                    av, bv, acc[nd], 0, 0, 0);
            }
        }

        // roll K prefetch
#pragma unroll
        for (int s = 0; s < 2; ++s)
            kf[s] = kfn[s];
    }

    // rowsum: rs2[qt] covers q = qt*16+l15 over this lane's key slots
#pragma unroll
    for (int qt = 0; qt < 4; ++qt) {
        float pr = rs2[qt].x + rs2[qt].y;
        pr += __shfl_xor(pr, 16);
        pr += __shfl_xor(pr, 32);
        if (quad == 0) Rbuf[w][qt * 16 + l15] = pr;
    }
    __syncthreads();
    if (t < 64) {
        float s = Rbuf[0][t] + Rbuf[1][t] + Rbuf[2][t] + Rbuf[3][t];
        Rfin[t] = 1.f / (s + 1e-6f);
    }
    __syncthreads();

    // store: O split hi/lo f16 (feeds the 2-product Wo GEMM)
#pragma unroll
    for (int r = 0; r < 4; ++r) {
        const int q = 16 * w + quad * 4 + r;
        const float inv = Rfin[q];
        const size_t base = (size_t)(b * TT + q0 + q) * DD + h * DK + l15;
#pragma unroll
        for (int nd = 0; nd < 4; ++nd) {
            float v = acc[nd][r] * inv;
            _Float16 hv = (_Float16)v;
            Oh[base + nd * 16] = hv;
            Ol[base + nd * 16] = (_Float16)(v - (float)hv);
        }
    }
}

// ---------------------------------------------------------------------------
extern "C" void kernel_launch(void* const* d_in, const int* in_sizes, int n_in,
                              void* d_out, int out_size, void* d_ws, size_t ws_size,
                              hipStream_t stream)
{
    const float* x  = (const float*)d_in[0];
    const float* Wq = (const float*)d_in[1];
    const float* Wk = (const float*)d_in[2];
    const float* Wv = (const float*)d_in[3];
    const float* Wo = (const float*)d_in[4];
    const float* bo = (const float*)d_in[5];
    float* out = (float*)d_out;

    const int M = BB * TT;   // 4096
    const int K = DD;

    const size_t MB = 1024 * 1024;
    char* ws = (char*)d_ws;
    // [0,8):   xh f16      -> Oh f16 (after QKV GEMM consumed xh)
    // [8,14):  W3h f16 = [Wq;Wk;Wv] rows (3072x1024, 6 MB)
    // [14,16): Woh f16 (persists)
    // [16,24): Qh f16 (normalized, [b][h][t][dk])
    // [24,32): Kh f16 (normalized)
    // [32,40): Vh f16 [row][1024] -> Ol f16 (after vtrans consumed Vh)
    // [40,48): Vt f16 [b][h][d][T]
    _Float16* xh  = (_Float16*)(ws);
    _Float16* W3h = (_Float16*)(ws + 8 * MB);
    _Float16* Woh = (_Float16*)(ws + 14 * MB);
    _Float16* Qh  = (_Float16*)(ws + 16 * MB);
    _Float16* Kh  = (_Float16*)(ws + 24 * MB);
    _Float16* Vh  = (_Float16*)(ws + 32 * MB);
    _Float16* Vt  = (_Float16*)(ws + 40 * MB);
    _Float16* Oh  = (_Float16*)(ws);            // xh dead after QKV GEMM
    _Float16* Ol  = (_Float16*)(ws + 32 * MB);  // Vh dead after vtrans

    dim3 gB(256);

    // 1) convert x + all weights to f16 (one launch)
    cvtall_kernel<<<4096, gB, 0, stream>>>(x, Wq, Wk, Wv, Wo, xh, W3h, Woh);

    // 2) fused QKV projection + l2norm epilogue -> Qh/Kh (normalized f16)
    //    and Vh (f16 passthrough). One 128x128-tile GEMM, B = [Wq;Wk;Wv].
    {
        const int nbx = 3072 / 128;              // 24
        const int nby = M / 128;                 // 32
        gemm_f16_128<1, 1><<<nbx * nby, gB, 0, stream>>>(
            xh, nullptr, W3h, nullptr, nullptr, Qh, Kh, Vh, nbx, K, 0);
    }

    // 3) V transpose (f16 in, f16 out)
    vtrans_kernel<<<dim3(TT / 64, HH, BB), gB, 0, stream>>>(Vh, Vt);

    // 4) fused angular attention -> O split f16 hi/lo
    attn_kernel<<<dim3(TT / 64, HH, BB), gB, 0, stream>>>(Qh, Kh, Vt, Oh, Ol);

    // 5) output projection: (Oh + Ol) @ Woh^T + bo
    {
        const int nbx = 1024 / 128;              // 8
        const int nby = M / 128;                 // 32
        gemm_f16_128<2, 0><<<nbx * nby, gB, 0, stream>>>(
            Oh, Ol, Woh, bo, out, nullptr, nullptr, nullptr, nbx, K, 1);
    }
}

// Round 7
// 279.108 us; speedup vs baseline: 1.4650x; 1.1134x over previous
//
#include <hip/hip_runtime.h>
#include <hip/hip_bf16.h>
#include <hip/hip_fp16.h>
#include <math.h>

// Problem constants
#define BB 2
#define TT 2048
#define DD 1024
#define HH 16
#define DK 64
#define KT 64             // keys per attention tile

typedef _Float16 f16x8 __attribute__((ext_vector_type(8)));
typedef __fp16 fp16x2 __attribute__((ext_vector_type(2)));
typedef __attribute__((ext_vector_type(4))) float f32x4;
typedef __attribute__((ext_vector_type(2))) float f32x2;

// async 16B global->LDS (lane i writes ldsbase + i*16)
static __device__ __forceinline__ void g2lds16(const void* g, void* l) {
    __builtin_amdgcn_global_load_lds(
        (const __attribute__((address_space(1))) unsigned int*)g,
        (__attribute__((address_space(3))) unsigned int*)l, 16, 0, 0);
}

// w = (1 - acos(clip(s,±0.999))/pi)^8 for a pair; rs accumulates pair sums.
// acos/pi via A&S 4.4.45 deg-3 (|err|<=5e-5 rad); reference's max(.,1e-6)
// is dead (clamp => t >= 0.0142). float2 ops lower to v_pk_* on gfx950.
// __builtin_amdgcn_sqrtf = raw v_sqrt_f32 (~1ulp, om in [1e-3,2] safe) —
// avoids the IEEE fixup sequence libm sqrtf emits without fast-math.
static __device__ __forceinline__ f32x2 w8pair(f32x2 s, f32x2& rs) {
    f32x2 ax;
    ax.x = fminf(fabsf(s.x), 0.999f);
    ax.y = fminf(fabsf(s.y), 0.999f);
    f32x2 p = ax * -0.0059617f + 0.0236380f;
    p = p * ax + (-0.0675180f);
    p = p * ax + 0.49997851f;
    f32x2 om = 1.0f - ax;
    f32x2 u;
    u.x = __builtin_amdgcn_sqrtf(om.x);
    u.y = __builtin_amdgcn_sqrtf(om.y);
    f32x2 uq = u * p;
    f32x2 e = 0.5f - uq;
    f32x2 t;
    t.x = 0.5f + copysignf(e.x, s.x);
    t.y = 0.5f + copysignf(e.y, s.y);
    f32x2 t2 = t * t;
    f32x2 t4 = t2 * t2;
    f32x2 t8 = t4 * t4;
    rs += t8;
    return t8;
}
// one-instruction f16 pair pack (RTZ; |err|<=2^-11 rel, fine for W)
static __device__ __forceinline__ int packh2(f32x2 v) {
    union { fp16x2 h; int i; } u;
    u.h = __builtin_amdgcn_cvt_pkrtz(v.x, v.y);
    return u.i;
}

// ---------------------------------------------------------------------------
// One-launch fp32 -> f16 convert.
// bid < 2048: x -> xh. Wq/Wk/Wv -> W3h rows (contiguous). Wo -> Wo2 rows
// DUPLICATED ([n][0..1023] = [n][1024..2047] = Wo[n]) for the K=2048
// single-product Wo GEMM. 8 elems/thread.
// ---------------------------------------------------------------------------
__global__ __launch_bounds__(256) void cvtall_kernel(
    const float* __restrict__ x,  const float* __restrict__ Wq,
    const float* __restrict__ Wk, const float* __restrict__ Wv,
    const float* __restrict__ Wo,
    _Float16* __restrict__ xh, _Float16* __restrict__ W3h,
    _Float16* __restrict__ Wo2)
{
    const int bid = blockIdx.x;
    const float* s; int wsel = -1, blk;
    if (bid < 2048) { s = x; blk = bid; }
    else {
        const int idx = bid - 2048;
        wsel = idx >> 9;          // 0..3
        blk  = idx & 511;
        s = (wsel == 0) ? Wq : (wsel == 1) ? Wk : (wsel == 2) ? Wv : Wo;
    }
    const int i = (blk * 256 + threadIdx.x) * 8;
    float4 a = *(const float4*)(s + i);
    float4 b = *(const float4*)(s + i + 4);
    union { _Float16 h[8]; int4 v; } u;
    u.h[0] = (_Float16)a.x; u.h[1] = (_Float16)a.y;
    u.h[2] = (_Float16)a.z; u.h[3] = (_Float16)a.w;
    u.h[4] = (_Float16)b.x; u.h[5] = (_Float16)b.y;
    u.h[6] = (_Float16)b.z; u.h[7] = (_Float16)b.w;
    if (wsel < 0)      *(int4*)(xh + i) = u.v;
    else if (wsel < 3) *(int4*)(W3h + (size_t)wsel * (DD * DD) + i) = u.v;
    else {
        const int n = i >> 10, k = i & 1023;
        _Float16* dst = Wo2 + (size_t)n * 2048 + k;
        *(int4*)dst          = u.v;
        *(int4*)(dst + 1024) = u.v;
    }
}

// ---------------------------------------------------------------------------
// m97-class f16 MFMA GEMM: 128x128 tile, BK=64, 4 waves (2x2, 64x64 each).
// Single product C = A @ B^T; chunk-major LDS [kc][row][8] (32 KB ->
// up to 5 blocks/CU, VGPR-limited in practice).
// EPI=0: C = acc + bias (fp32 out, stride 1024).
// EPI=1: fused QKV epilogue. seg(n0g>>10): 0 -> Qh, 1 -> Kh (in-register
//   l2norm: shfl_xor over 16-lane group + v_rsq; f16 [b][h][t][dk]);
//   2 -> V written DIRECTLY TRANSPOSED to Vt f16 [b][h][d][T] (each lane's
//   acc column = 4 consecutive tokens -> aligned int2 stores; vtrans
//   kernel deleted). RTN converts preserved.
// 1D grid + XCD-bijective swizzle (nwg % 8 == 0).
// ---------------------------------------------------------------------------
template<int EPI>
__global__ __launch_bounds__(256, 3) void gemm_f16_128(
    const _Float16* __restrict__ Ah_g, const _Float16* __restrict__ B_g,
    const float* __restrict__ bias, float* __restrict__ C,
    _Float16* __restrict__ Qh, _Float16* __restrict__ Kh,
    _Float16* __restrict__ Vt,
    int nbx, int K, int hasBias)
{
    __shared__ _Float16 Ahs[8][128][8];   // 16 KB
    __shared__ _Float16 Bhs[8][128][8];   // 16 KB

    // XCD-bijective swizzle (nwg multiple of 8)
    const int nwg  = gridDim.x;
    const int wgid = blockIdx.x;
    const int cpx  = nwg >> 3;
    const int swz  = (wgid & 7) * cpx + (wgid >> 3);
    const int by   = swz / nbx;
    const int bx   = swz - by * nbx;

    const int t    = threadIdx.x;
    const int m0   = by * 128;
    const int n0g  = bx * 128;
    const int seg  = n0g >> 10;
    const int n0   = n0g & 1023;

    const int lane = t & 63;
    const int w    = t >> 6;
    const int wm   = w >> 1;
    const int wn   = w & 1;
    const int l15  = lane & 15;
    const int quad = lane >> 4;

    f32x4 acc[4][4];
#pragma unroll
    for (int i = 0; i < 4; ++i)
#pragma unroll
        for (int j = 0; j < 4; ++j) acc[i][j] = (f32x4)0.f;

    for (int k0 = 0; k0 < K; k0 += 64) {
        __syncthreads();   // previous chunk's frag reads done
        // staging: wave w handles chunks cc = 2w, 2w+1 (128 rows = 2 halves)
#pragma unroll
        for (int i = 0; i < 2; ++i) {
            const int cc = w * 2 + i;
#pragma unroll
            for (int half = 0; half < 2; ++half) {
                g2lds16(Ah_g + (size_t)(m0 + half * 64 + lane) * K + k0 + cc * 8,
                        &Ahs[cc][half * 64][0]);
                g2lds16(B_g + (size_t)(n0g + half * 64 + lane) * K + k0 + cc * 8,
                        &Bhs[cc][half * 64][0]);
            }
        }
        __syncthreads();   // vmcnt drained

#pragma unroll
        for (int kh = 0; kh < 2; ++kh) {
            f16x8 ah[4], bh[4];
#pragma unroll
            for (int tm = 0; tm < 4; ++tm)
                ah[tm] = *(const f16x8*)&Ahs[kh * 4 + quad][wm * 64 + tm * 16 + l15][0];
#pragma unroll
            for (int tn = 0; tn < 4; ++tn)
                bh[tn] = *(const f16x8*)&Bhs[kh * 4 + quad][wn * 64 + tn * 16 + l15][0];
#pragma unroll
            for (int tm = 0; tm < 4; ++tm)
#pragma unroll
                for (int tn = 0; tn < 4; ++tn)
                    acc[tm][tn] = __builtin_amdgcn_mfma_f32_16x16x32_f16(
                        ah[tm], bh[tn], acc[tm][tn], 0, 0, 0);
        }
    }

    if (EPI == 0) {
#pragma unroll
        for (int tm = 0; tm < 4; ++tm)
#pragma unroll
            for (int tn = 0; tn < 4; ++tn) {
                const int col  = n0 + wn * 64 + tn * 16 + l15;
                const float bv = hasBias ? bias[col] : 0.f;
                const int rowb = m0 + wm * 64 + tm * 16 + quad * 4;
#pragma unroll
                for (int r = 0; r < 4; ++r)
                    C[(size_t)(rowb + r) * 1024 + col] = acc[tm][tn][r] + bv;
            }
    } else {
        if (seg < 2) {
            // normalize each row's 64-wide head segment, emit f16 [b][h][t][dk]
            _Float16* __restrict__ dstb = (seg == 0) ? Qh : Kh;
            const int hh = (n0 >> 6) + wn;   // head index
#pragma unroll
            for (int tm = 0; tm < 4; ++tm) {
#pragma unroll
                for (int r = 0; r < 4; ++r) {
                    float ss = 0.f;
#pragma unroll
                    for (int tn = 0; tn < 4; ++tn) {
                        const float v = acc[tm][tn][r];
                        ss += v * v;
                    }
                    ss += __shfl_xor(ss, 1);
                    ss += __shfl_xor(ss, 2);
                    ss += __shfl_xor(ss, 4);
                    ss += __shfl_xor(ss, 8);
                    const float inv = __builtin_amdgcn_rsqf(fmaxf(ss, 1e-24f));
                    const int row = m0 + wm * 64 + tm * 16 + quad * 4 + r;
                    const int b   = row >> 11;
                    const int tt  = row & 2047;
                    _Float16* dst = dstb + ((size_t)(b * HH + hh) * TT + tt) * DK;
#pragma unroll
                    for (int tn = 0; tn < 4; ++tn)
                        dst[tn * 16 + l15] = (_Float16)(acc[tm][tn][r] * inv);
                }
            }
        } else {
            // V: write transposed f16 [b][h][d][T] directly.
            // col -> (h = const across tn-varying low 6 bits? no: h fixed,
            // d = tn*16+l15); rows -> 4 consecutive tokens per lane.
            const int hh = (n0 >> 6) + wn;
            const int rowb = m0 + wm * 64 + quad * 4;   // + tm*16
            const int bb  = rowb >> 11;                 // tile never crosses b
            const int tt0 = rowb & 2047;
#pragma unroll
            for (int tn = 0; tn < 4; ++tn) {
                const int d = tn * 16 + l15;
                _Float16* dst = Vt + ((size_t)(bb * HH + hh) * DK + d) * TT;
#pragma unroll
                for (int tm = 0; tm < 4; ++tm) {
                    union { _Float16 h[4]; int2 v; } uu;
                    uu.h[0] = (_Float16)acc[tm][tn][0];
                    uu.h[1] = (_Float16)acc[tm][tn][1];
                    uu.h[2] = (_Float16)acc[tm][tn][2];
                    uu.h[3] = (_Float16)acc[tm][tn][3];
                    *(int2*)(dst + tt0 + tm * 16) = uu.v;
                }
            }
        }
    }
}

// ---------------------------------------------------------------------------
// MFMA angular attention v10 — all-f16. Grid (T/64, H, B), 256 threads.
// KT=64, LDS 36.1 KB -> 4 blocks/CU, grid 1024 = exactly 4/CU (all
// resident). ONE barrier per tile (Ws + Vts double-buffered; V staged a
// full tile ahead; K frags prefetched in registers).
// v10: raw v_sqrt in transform; O emitted hi/lo into ONE [M][2048] buffer
// (cols 0-1023 = hi, 1024-2047 = lo) feeding the K=2048 Wo GEMM.
// ---------------------------------------------------------------------------
__global__ __launch_bounds__(256, 4) void attn_kernel(
    const _Float16* __restrict__ Qh_g, const _Float16* __restrict__ Kh_g,
    const _Float16* __restrict__ Vt_g, _Float16* __restrict__ O2)
{
    __shared__ _Float16 Vts[2][8][64][8];  // [buf][key-chunk][d][8] 16384 B
    __shared__ _Float16 Ws[2][64][72];     // [buf][q][key]          18432 B
    __shared__ float Rbuf[4][64];          //                         1024 B
    __shared__ float Rfin[64];             //                          256 B

    const int t    = threadIdx.x;
    const int lane = t & 63;
    const int w    = t >> 6;
    const int l15  = lane & 15;
    const int quad = lane >> 4;
    const int q0   = blockIdx.x * 64;
    const int h    = blockIdx.y;
    const int b    = blockIdx.z;
    const size_t bh = (size_t)(b * HH + h);

    const _Float16* kh_g = Kh_g + bh * TT * DK;
    const _Float16* vt_g = Vt_g + bh * (size_t)DK * TT;

    // Q fragments in registers (loaded once, L2-served)
    f16x8 qf[4][2];
#pragma unroll
    for (int qt = 0; qt < 4; ++qt)
#pragma unroll
        for (int s = 0; s < 2; ++s)
            qf[qt][s] = *(const f16x8*)(Qh_g + (bh * TT + q0 + qt * 16 + l15) * DK
                                        + s * 32 + quad * 8);

    // K fragments for tile 0 (wave's 16 keys; 16B contiguous per lane)
    f16x8 kf[2], kfn[2];
#pragma unroll
    for (int s = 0; s < 2; ++s) {
        kf[s] = *(const f16x8*)(kh_g
            + (size_t)(w * 16 + l15) * DK + s * 32 + quad * 8);
        kfn[s] = kf[s];
    }

    // stage V tile 0 into buffer 0 (8 KB; wave w covers chunks 2w, 2w+1)
#pragma unroll
    for (int j = 0; j < 2; ++j) {
        const int kc = w * 2 + j;
        g2lds16(vt_g + (size_t)lane * TT + kc * 8, &Vts[0][kc][0][0]);
    }

    f32x4 acc[4];    // O[16q x 64d] for q-tile w
#pragma unroll
    for (int j = 0; j < 4; ++j) acc[j] = (f32x4)0.f;
    f32x2 rs2[4];
#pragma unroll
    for (int j = 0; j < 4; ++j) rs2[j] = (f32x2)0.f;

    int p = 0;
    for (int k0 = 0; k0 < TT; k0 += KT, p ^= 1) {
        const int kn = k0 + KT;
        if (kn < TT) {
            // prefetch K fragments for tile t+1 (consumed after kf roll)
#pragma unroll
            for (int s = 0; s < 2; ++s)
                kfn[s] = *(const f16x8*)(kh_g
                    + (size_t)(kn + w * 16 + l15) * DK + s * 32 + quad * 8);
        }

        // Phase A: S^T for wave's 16 keys x 64 q, transform, write Ws[p]
#pragma unroll
        for (int qt = 0; qt < 4; ++qt) {
            f32x4 c_ = (f32x4)0.f;
#pragma unroll
            for (int s = 0; s < 2; ++s)
                c_ = __builtin_amdgcn_mfma_f32_16x16x32_f16(
                    kf[s], qf[qt][s], c_, 0, 0, 0);
            f32x2 p01, p23;
            p01.x = c_[0]; p01.y = c_[1];
            p23.x = c_[2]; p23.y = c_[3];
            f32x2 w01 = w8pair(p01, rs2[qt]);
            f32x2 w23 = w8pair(p23, rs2[qt]);
            int2 pk;
            pk.x = packh2(w01);
            pk.y = packh2(w23);
            *(int2*)&Ws[p][qt * 16 + l15][w * 16 + quad * 4] = pk;
        }
        __syncthreads();   // BAR(t): Ws[p] ready; V[t] arrived (staged t-1);
                           // B(t-1)'s Ws[p^1]/Vts[p^1] reads drained

        if (kn < TT) {
            // stage V[t+1] into the other buffer (consumed after BAR(t+1))
#pragma unroll
            for (int j = 0; j < 2; ++j) {
                const int kc = w * 2 + j;
                g2lds16(vt_g + (size_t)lane * TT + kn + kc * 8,
                        &Vts[p ^ 1][kc][0][0]);
            }
        }

        // Phase B: PV for q-tile w over the tile's 64 keys from Vts[p]
#pragma unroll
        for (int kstep = 0; kstep < 2; ++kstep) {
            f16x8 av = *(const f16x8*)&Ws[p][16 * w + l15][kstep * 32 + quad * 8];
#pragma unroll
            for (int nd = 0; nd < 4; ++nd) {
                f16x8 bv = *(const f16x8*)&Vts[p][kstep * 4 + quad][nd * 16 + l15][0];
                acc[nd] = __builtin_amdgcn_mfma_f32_16x16x32_f16(
                    av, bv, acc[nd], 0, 0, 0);
            }
        }

        // roll K prefetch
#pragma unroll
        for (int s = 0; s < 2; ++s)
            kf[s] = kfn[s];
    }

    // rowsum: rs2[qt] covers q = qt*16+l15 over this lane's key slots
#pragma unroll
    for (int qt = 0; qt < 4; ++qt) {
        float pr = rs2[qt].x + rs2[qt].y;
        pr += __shfl_xor(pr, 16);
        pr += __shfl_xor(pr, 32);
        if (quad == 0) Rbuf[w][qt * 16 + l15] = pr;
    }
    __syncthreads();
    if (t < 64) {
        float s = Rbuf[0][t] + Rbuf[1][t] + Rbuf[2][t] + Rbuf[3][t];
        Rfin[t] = 1.f / (s + 1e-6f);
    }
    __syncthreads();

    // store: O hi/lo f16 into [M][2048] (hi cols 0-1023, lo 1024-2047)
#pragma unroll
    for (int r = 0; r < 4; ++r) {
        const int q = 16 * w + quad * 4 + r;
        const float inv = Rfin[q];
        const size_t base = (size_t)(b * TT + q0 + q) * 2048 + h * DK + l15;
#pragma unroll
        for (int nd = 0; nd < 4; ++nd) {
            float v = acc[nd][r] * inv;
            _Float16 hv = (_Float16)v;
            O2[base + nd * 16]        = hv;
            O2[base + 1024 + nd * 16] = (_Float16)(v - (float)hv);
        }
    }
}

// ---------------------------------------------------------------------------
extern "C" void kernel_launch(void* const* d_in, const int* in_sizes, int n_in,
                              void* d_out, int out_size, void* d_ws, size_t ws_size,
                              hipStream_t stream)
{
    const float* x  = (const float*)d_in[0];
    const float* Wq = (const float*)d_in[1];
    const float* Wk = (const float*)d_in[2];
    const float* Wv = (const float*)d_in[3];
    const float* Wo = (const float*)d_in[4];
    const float* bo = (const float*)d_in[5];
    float* out = (float*)d_out;

    const int M = BB * TT;   // 4096

    const size_t MB = 1024 * 1024;
    char* ws = (char*)d_ws;
    // [0,8):   xh f16      }-> O2 f16 [M][2048] at [0,16) after QKV GEMM
    // [8,14):  W3h f16     }   (xh, W3h dead by then)
    // [16,20): Wo2 f16 (1024 x 2048, duplicated rows; persists)
    // [24,32): Qh f16 (normalized, [b][h][t][dk])
    // [32,40): Kh f16 (normalized)
    // [40,48): Vt f16 [b][h][d][T] (written by QKV GEMM epilogue)
    _Float16* xh  = (_Float16*)(ws);
    _Float16* W3h = (_Float16*)(ws + 8 * MB);
    _Float16* Wo2 = (_Float16*)(ws + 16 * MB);
    _Float16* Qh  = (_Float16*)(ws + 24 * MB);
    _Float16* Kh  = (_Float16*)(ws + 32 * MB);
    _Float16* Vt  = (_Float16*)(ws + 40 * MB);
    _Float16* O2  = (_Float16*)(ws);            // xh/W3h dead after QKV GEMM

    dim3 gB(256);

    // 1) convert x + weights to f16 (one launch; Wo duplicated per row)
    cvtall_kernel<<<4096, gB, 0, stream>>>(x, Wq, Wk, Wv, Wo, xh, W3h, Wo2);

    // 2) fused QKV projection: l2norm epilogue -> Qh/Kh; V -> Vt transposed
    {
        const int nbx = 3072 / 128;              // 24
        const int nby = M / 128;                 // 32
        gemm_f16_128<1><<<nbx * nby, gB, 0, stream>>>(
            xh, W3h, nullptr, nullptr, Qh, Kh, Vt, nbx, DD, 0);
    }

    // 3) fused angular attention -> O2 hi/lo f16 [M][2048]
    attn_kernel<<<dim3(TT / 64, HH, BB), gB, 0, stream>>>(Qh, Kh, Vt, O2);

    // 4) output projection: O2 @ Wo2^T + bo  (K=2048 == hi+lo products)
    {
        const int nbx = 1024 / 128;              // 8
        const int nby = M / 128;                 // 32
        gemm_f16_128<0><<<nbx * nby, gB, 0, stream>>>(
            O2, Wo2, bo, out, nullptr, nullptr, nullptr, nbx, 2048, 1);
    }
}